// Round 1
// baseline (1083.937 us; speedup 1.0000x reference)
//
#include <hip/hip_runtime.h>
#include <math.h>

#define PX 4096   // 64*64
#define TT 32
#define DD 32
#define CC 64     // 2*D

__device__ __forceinline__ float gelu_tanh(float x) {
    float x3 = x * x * x;
    float z = 0.7978845608028654f * (x + 0.044715f * x3);
    return 0.5f * x * (1.0f + tanhf(z));
}

// ---------------- K1: LN1 over 64 channels (concat re/im), NCHW out ----------
__global__ __launch_bounds__(256) void k1_ln1(
        const float* __restrict__ xre, const float* __restrict__ xim,
        const float* __restrict__ g, const float* __restrict__ b,
        float* __restrict__ xn) {
    int gid = blockIdx.x * 256 + threadIdx.x;   // t*4096 + px
    int t = gid >> 12, px = gid & 4095;
    const float* pr = xre + (size_t)t * DD * PX + px;
    const float* pi = xim + (size_t)t * DD * PX + px;
    float s = 0.f, ss = 0.f;
    #pragma unroll
    for (int d = 0; d < DD; ++d) {
        float vr = pr[d * PX], vi = pi[d * PX];
        s += vr + vi; ss += vr * vr + vi * vi;
    }
    float m = s * (1.f / 64.f);
    float var = ss * (1.f / 64.f) - m * m;
    float rs = rsqrtf(var + 1e-5f);
    float* o = xn + (size_t)t * CC * PX + px;
    #pragma unroll
    for (int d = 0; d < DD; ++d) {
        o[d * PX]        = (pr[d * PX] - m) * rs * g[d]      + b[d];
        o[(d + DD) * PX] = (pi[d * PX] - m) * rs * g[d + DD] + b[d + DD];
    }
}

// ---------------- K2: 3x3 SAME conv 64->64, one (n,o) plane per block --------
__global__ __launch_bounds__(256) void k2_conv(
        const float* __restrict__ xn, const float* __restrict__ w,
        const float* __restrict__ bias, float* __restrict__ xs) {
    __shared__ float pl[66 * 66];
    int n = blockIdx.x >> 6;
    int o = blockIdx.x & 63;
    int tid = threadIdx.x;
    int wcol = tid & 63, grp = tid >> 6;
    int r0 = grp * 16;
    float acc[16];
    #pragma unroll
    for (int i = 0; i < 16; ++i) acc[i] = 0.f;
    const float* wb = w + (size_t)o * 64 * 9;
    for (int ic = 0; ic < 64; ++ic) {
        __syncthreads();   // protect pl from previous iteration readers
        const float* src = xn + ((size_t)n * 64 + ic) * PX;
        for (int idx = tid; idx < 66 * 66; idx += 256) {
            int rr = idx / 66, cc2 = idx - rr * 66;
            int ir = rr - 1, jc = cc2 - 1;
            float v = 0.f;
            if ((unsigned)ir < 64u && (unsigned)jc < 64u) v = src[ir * 64 + jc];
            pl[idx] = v;
        }
        __syncthreads();
        float wk[9];
        #pragma unroll
        for (int q = 0; q < 9; ++q) wk[q] = wb[ic * 9 + q];
        #pragma unroll
        for (int s = 0; s < 18; ++s) {          // input rows r0-1 .. r0+16
            int prow = r0 + s;                   // halo row index
            float L = pl[prow * 66 + wcol];
            float M = pl[prow * 66 + wcol + 1];
            float R = pl[prow * 66 + wcol + 2];
            #pragma unroll
            for (int kh = 0; kh < 3; ++kh) {
                int os = s - kh;                 // output row - r0
                if (os >= 0 && os < 16)
                    acc[os] += wk[kh * 3] * L + wk[kh * 3 + 1] * M + wk[kh * 3 + 2] * R;
            }
        }
    }
    float bo = bias[o];
    float* dst = xs + ((size_t)n * 64 + o) * PX + wcol;
    #pragma unroll
    for (int i = 0; i < 16; ++i) dst[(r0 + i) * 64] = acc[i] + bo;
}

// ---------------- K3: per-(t,c) spatial mean -------------------------------
__global__ __launch_bounds__(256) void k3_mean(
        const float* __restrict__ xs, float* __restrict__ mean) {
    __shared__ float red[256];
    int plane = blockIdx.x;            // t*64 + c
    const float* p = xs + (size_t)plane * PX;
    float s = 0.f;
    for (int i = threadIdx.x; i < PX; i += 256) s += p[i];
    red[threadIdx.x] = s; __syncthreads();
    for (int st = 128; st > 0; st >>= 1) {
        if (threadIdx.x < st) red[threadIdx.x] += red[threadIdx.x + st];
        __syncthreads();
    }
    if (threadIdx.x == 0) mean[plane] = red[0] * (1.f / 4096.f);
}

// ---------------- K4: decay/forcing tables + flux scan ----------------------
__global__ __launch_bounds__(256) void k4_ops(
        const float* __restrict__ dt, const float* __restrict__ lam_re,
        const float* __restrict__ lam_im, const float* __restrict__ alpha,
        const float* __restrict__ wre, const float* __restrict__ wim,
        const float* __restrict__ mean, float* __restrict__ tabs,
        float* __restrict__ outflux) {
    int tid = threadIdx.x;
    for (int idx = tid; idx < 1024; idx += 256) {
        int t = idx >> 5, d = idx & 31;
        float x = lam_re[d];
        float sp = (x > 0.f) ? x + log1pf(expf(-x)) : log1pf(expf(x));
        float lr = -sp, li = lam_im[d];
        float dtv = dt[t];
        float er = expf(lr * dtv);
        float dr = er * cosf(li * dtv);
        float di = er * sinf(li * dtv);
        float den = lr * lr + li * li;
        float fr = ((dr - 1.f) * lr + di * li) / den;
        float fi = (di * lr - (dr - 1.f) * li) / den;
        tabs[idx] = dr; tabs[1024 + idx] = di;
        tabs[2048 + idx] = fr; tabs[3072 + idx] = fi;
    }
    if (tid < 32) {
        int d = tid;
        float a = 1.f / (1.f + expf(-alpha[d]));
        float yr = 0.f, yi = 0.f;
        for (int t = 0; t < 32; ++t) {
            float xr = 0.f, xi = 0.f;
            for (int k = 0; k < 32; ++k) {
                float mr = mean[t * 64 + k], mi = mean[t * 64 + 32 + k];
                float wr = wre[k * 32 + d], wi = wim[k * 32 + d];
                xr += mr * wr - mi * wi;
                xi += mr * wi + mi * wr;
            }
            yr = a * yr + xr; yi = a * yi + xi;
        }
        outflux[d] = yr; outflux[32 + d] = yi;
    }
}

// ---------------- K5: enc matmul + time scan + noise + dec matmul -----------
// block = 8 px * 32 d; loops t sequentially. Writes xo pixel-major (t,px,c).
__global__ __launch_bounds__(256) void k5_seq(
        const float* __restrict__ xs,
        const float* __restrict__ enc_re, const float* __restrict__ enc_im,
        const float* __restrict__ dec_re, const float* __restrict__ dec_im,
        const float* __restrict__ tabs, const float* __restrict__ dt,
        const float* __restrict__ eps_re, const float* __restrict__ eps_im,
        float* __restrict__ xo) {
    __shared__ float xsl[8 * 64];
    __shared__ float uol[8 * 64];
    int tid = threadIdx.x;
    int lpx = tid >> 5, d = tid & 31;
    int pxbase = blockIdx.x * 8;
    float eR[32], eI[32], dR[32], dI[32];
    #pragma unroll
    for (int k = 0; k < 32; ++k) {
        eR[k] = enc_re[k * 32 + d]; eI[k] = enc_im[k * 32 + d];
        dR[k] = dec_re[k * 32 + d]; dI[k] = dec_im[k * 32 + d];
    }
    float Yr = 0.f, Yi = 0.f;
    for (int t = 0; t < TT; ++t) {
        for (int idx = tid; idx < 512; idx += 256) {
            int c = idx >> 3, p = idx & 7;
            xsl[p * 64 + c] = xs[((size_t)t * 64 + c) * PX + pxbase + p];
        }
        __syncthreads();
        float ur = 0.f, ui = 0.f;
        #pragma unroll
        for (int k = 0; k < 32; ++k) {
            float xr = xsl[lpx * 64 + k], xi = xsl[lpx * 64 + 32 + k];
            ur += xr * eR[k] - xi * eI[k];
            ui += xr * eI[k] + xi * eR[k];
        }
        float drr = tabs[t * 32 + d],        dii = tabs[1024 + t * 32 + d];
        float fr  = tabs[2048 + t * 32 + d], fi  = tabs[3072 + t * 32 + d];
        float usr = ur * fr - ui * fi;
        float usi = ur * fi + ui * fr;
        float nYr = drr * Yr - dii * Yi + usr;
        float nYi = drr * Yi + dii * Yr + usi;
        Yr = nYr; Yi = nYi;
        float s = 0.01f * sqrtf(dt[t]);
        size_t ei = ((size_t)t * PX + pxbase + lpx) * 32 + d;
        float epr = eps_re[ei], epi = eps_im[ei];
        float nr = Yr * epr - Yi * epi;
        float ni = Yr * epi + Yi * epr;
        uol[lpx * 64 + d]      = Yr + s * nr;
        uol[lpx * 64 + 32 + d] = Yi + s * ni;
        __syncthreads();
        float xr2 = 0.f, xi2 = 0.f;
        #pragma unroll
        for (int k = 0; k < 32; ++k) {
            float ar = uol[lpx * 64 + k], ai = uol[lpx * 64 + 32 + k];
            xr2 += ar * dR[k] - ai * dI[k];
            xi2 += ar * dI[k] + ai * dR[k];
        }
        size_t ob = ((size_t)t * PX + pxbase + lpx) * 64;
        xo[ob + d]      = xr2;
        xo[ob + 32 + d] = xi2;
    }
}

// ---------------- K6: LN2 + gated MoE MLP + residual/final write ------------
// block = 16 pixels of one t; per-expert w1/w2 staged to LDS.
__global__ __launch_bounds__(256) void k6_moe(
        const float* __restrict__ xo,
        const float* __restrict__ g2, const float* __restrict__ b2ln,
        const float* __restrict__ wg, const float* __restrict__ w1,
        const float* __restrict__ b1, const float* __restrict__ w2,
        const float* __restrict__ b2m,
        const float* __restrict__ xre, const float* __restrict__ xim,
        float* __restrict__ out) {
    __shared__ float fld[16 * 64];
    __shared__ float w1l[64 * 128];
    __shared__ float w2l[128 * 64];
    __shared__ float hdn[16 * 132];
    __shared__ float gate[16 * 4];
    __shared__ float stat[32];
    int tid = threadIdx.x;
    int t = blockIdx.x >> 8;
    int px0 = (blockIdx.x & 255) * 16;
    // A: load 16 contiguous pixel rows (1024 floats)
    {
        const float4* src = (const float4*)(xo + ((size_t)t * PX + px0) * 64);
        ((float4*)fld)[tid] = src[tid];
    }
    __syncthreads();
    // B1: LN2 stats
    if (tid < 16) {
        float s = 0.f, ss = 0.f;
        #pragma unroll
        for (int c = 0; c < 64; ++c) { float v = fld[tid * 64 + c]; s += v; ss += v * v; }
        float m = s * (1.f / 64.f);
        float var = ss * (1.f / 64.f) - m * m;
        stat[tid] = m; stat[16 + tid] = rsqrtf(var + 1e-5f);
    }
    __syncthreads();
    // B2: normalize in place
    #pragma unroll
    for (int r = 0; r < 4; ++r) {
        int v = r * 256 + tid;
        int p = v >> 6, c = v & 63;
        fld[v] = (fld[v] - stat[p]) * stat[16 + p] * g2[c] + b2ln[c];
    }
    __syncthreads();
    // B3: gate logits + softmax
    if (tid < 64) {
        int p = tid >> 2, e = tid & 3;
        float acc = 0.f;
        #pragma unroll
        for (int c = 0; c < 64; ++c) acc += fld[p * 64 + c] * wg[c * 4 + e];
        gate[tid] = acc;
    }
    __syncthreads();
    if (tid < 16) {
        float l0 = gate[tid*4], l1 = gate[tid*4+1], l2 = gate[tid*4+2], l3 = gate[tid*4+3];
        float mx = fmaxf(fmaxf(l0, l1), fmaxf(l2, l3));
        float e0 = expf(l0-mx), e1 = expf(l1-mx), e2 = expf(l2-mx), e3 = expf(l3-mx);
        float inv = 1.f / (e0 + e1 + e2 + e3);
        gate[tid*4] = e0*inv; gate[tid*4+1] = e1*inv; gate[tid*4+2] = e2*inv; gate[tid*4+3] = e3*inv;
    }
    float delta[4] = {0.f, 0.f, 0.f, 0.f};
    int pD = tid >> 4, cj = tid & 15;     // phase D: 1 px * 4 c
    int pxgC = tid >> 5, fj = tid & 31;   // phase C: 2 px * 4 f
    for (int e = 0; e < 4; ++e) {
        __syncthreads();
        const float* w1e = w1 + (size_t)e * 64 * 128;
        const float* w2e = w2 + (size_t)e * 128 * 64;
        for (int i = tid; i < 8192; i += 256) { w1l[i] = w1e[i]; w2l[i] = w2e[i]; }
        __syncthreads();
        // phase C: hdn = gelu(f @ w1e + b1e)
        {
            int p0 = pxgC * 2;
            float bb0 = b1[e*128 + fj*4], bb1 = b1[e*128 + fj*4 + 1];
            float bb2 = b1[e*128 + fj*4 + 2], bb3 = b1[e*128 + fj*4 + 3];
            float a0x = bb0, a0y = bb1, a0z = bb2, a0w = bb3;
            float a1x = bb0, a1y = bb1, a1z = bb2, a1w = bb3;
            #pragma unroll 8
            for (int c = 0; c < 64; ++c) {
                float f0 = fld[p0 * 64 + c], f1 = fld[p0 * 64 + 64 + c];
                float4 wv = *(const float4*)&w1l[c * 128 + fj * 4];
                a0x += f0 * wv.x; a0y += f0 * wv.y; a0z += f0 * wv.z; a0w += f0 * wv.w;
                a1x += f1 * wv.x; a1y += f1 * wv.y; a1z += f1 * wv.z; a1w += f1 * wv.w;
            }
            *(float4*)&hdn[p0 * 132 + fj * 4] =
                make_float4(gelu_tanh(a0x), gelu_tanh(a0y), gelu_tanh(a0z), gelu_tanh(a0w));
            *(float4*)&hdn[(p0 + 1) * 132 + fj * 4] =
                make_float4(gelu_tanh(a1x), gelu_tanh(a1y), gelu_tanh(a1z), gelu_tanh(a1w));
        }
        __syncthreads();
        // phase D: delta += gate_e * (hdn @ w2e + b2e)
        {
            float ax = 0.f, ay = 0.f, az = 0.f, aw = 0.f;
            #pragma unroll 8
            for (int f = 0; f < 128; ++f) {
                float h = hdn[pD * 132 + f];
                float4 wv = *(const float4*)&w2l[f * 64 + cj * 4];
                ax += h * wv.x; ay += h * wv.y; az += h * wv.z; aw += h * wv.w;
            }
            float gt = gate[pD * 4 + e];
            delta[0] += gt * (ax + b2m[e * 64 + cj * 4]);
            delta[1] += gt * (ay + b2m[e * 64 + cj * 4 + 1]);
            delta[2] += gt * (az + b2m[e * 64 + cj * 4 + 2]);
            delta[3] += gt * (aw + b2m[e * 64 + cj * 4 + 3]);
        }
    }
    __syncthreads();
    float* dl = w1l;   // reuse as delta buffer [16][64]
    *(float4*)&dl[pD * 64 + cj * 4] = make_float4(delta[0], delta[1], delta[2], delta[3]);
    __syncthreads();
    // final: out = x + (xoc + delta), transposed write (16-px runs)
    #pragma unroll
    for (int r = 0; r < 4; ++r) {
        int v = r * 256 + tid;
        int p = v & 15, c = v >> 4;
        int gpx = px0 + p;
        float val = fld[p * 64 + c] + dl[p * 64 + c];
        size_t xi_ = ((size_t)t * 32 + (c & 31)) * PX + gpx;
        float xv = (c < 32) ? xre[xi_] : xim[xi_];
        out[(size_t)(c < 32 ? 0 : 4194304) + xi_] = val + xv;
    }
}

extern "C" void kernel_launch(void* const* d_in, const int* in_sizes, int n_in,
                              void* d_out, int out_size, void* d_ws, size_t ws_size,
                              hipStream_t stream) {
    const float* xre   = (const float*)d_in[0];
    const float* xim   = (const float*)d_in[1];
    const float* dt    = (const float*)d_in[2];
    const float* epsre = (const float*)d_in[3];
    const float* epsim = (const float*)d_in[4];
    const float* ln1g  = (const float*)d_in[5];
    const float* ln1b  = (const float*)d_in[6];
    const float* ln2g  = (const float*)d_in[7];
    const float* ln2b  = (const float*)d_in[8];
    const float* convw = (const float*)d_in[9];
    const float* convb = (const float*)d_in[10];
    const float* encre = (const float*)d_in[11];
    const float* encim = (const float*)d_in[12];
    const float* decre = (const float*)d_in[13];
    const float* decim = (const float*)d_in[14];
    const float* lamre = (const float*)d_in[15];
    const float* lamim = (const float*)d_in[16];
    const float* alpha = (const float*)d_in[17];
    const float* fwre  = (const float*)d_in[18];
    const float* fwim  = (const float*)d_in[19];
    const float* wg    = (const float*)d_in[20];
    const float* w1    = (const float*)d_in[21];
    const float* b1    = (const float*)d_in[22];
    const float* w2    = (const float*)d_in[23];
    const float* b2    = (const float*)d_in[24];
    float* out = (float*)d_out;

    float* ws   = (float*)d_ws;
    float* xn   = ws;                   // 8388608 floats (also reused for xo)
    float* xs   = ws + 8388608;         // 8388608 floats
    float* mean = ws + 16777216;        // 2048 floats
    float* tabs = ws + 16779264;        // 4096 floats

    k1_ln1<<<512, 256, 0, stream>>>(xre, xim, ln1g, ln1b, xn);
    k2_conv<<<2048, 256, 0, stream>>>(xn, convw, convb, xs);
    k3_mean<<<2048, 256, 0, stream>>>(xs, mean);
    k4_ops<<<1, 256, 0, stream>>>(dt, lamre, lamim, alpha, fwre, fwim, mean,
                                  tabs, out + 8388608);
    k5_seq<<<512, 256, 0, stream>>>(xs, encre, encim, decre, decim, tabs, dt,
                                    epsre, epsim, xn);
    k6_moe<<<8192, 256, 0, stream>>>(xn, ln2g, ln2b, wg, w1, b1, w2, b2,
                                     xre, xim, out);
}

// Round 3
// 735.862 us; speedup vs baseline: 1.4730x; 1.4730x over previous
//
#include <hip/hip_runtime.h>
#include <math.h>

#define PX 4096   // 64*64
#define TT 32
#define DD 32
#define CC 64     // 2*D

typedef __attribute__((ext_vector_type(8))) short short8v;
typedef __attribute__((ext_vector_type(4))) float f32x4;

__device__ __forceinline__ float gelu_tanh(float x) {
    float x3 = x * x * x;
    float z = 0.7978845608028654f * (x + 0.044715f * x3);
    return 0.5f * x * (1.0f + tanhf(z));
}

__device__ __forceinline__ unsigned short f2b(float x) {
    union { float f; unsigned u; } v; v.f = x;
    unsigned r = v.u + 0x7FFF + ((v.u >> 16) & 1);
    return (unsigned short)(r >> 16);
}

// ---------------- K1: LN1 over 64 channels (concat re/im), NCHW out ----------
__global__ __launch_bounds__(256) void k1_ln1(
        const float* __restrict__ xre, const float* __restrict__ xim,
        const float* __restrict__ g, const float* __restrict__ b,
        float* __restrict__ xn) {
    int gid = blockIdx.x * 256 + threadIdx.x;   // t*4096 + px
    int t = gid >> 12, px = gid & 4095;
    const float* pr = xre + (size_t)t * DD * PX + px;
    const float* pi = xim + (size_t)t * DD * PX + px;
    float s = 0.f, ss = 0.f;
    #pragma unroll
    for (int d = 0; d < DD; ++d) {
        float vr = pr[d * PX], vi = pi[d * PX];
        s += vr + vi; ss += vr * vr + vi * vi;
    }
    float m = s * (1.f / 64.f);
    float var = ss * (1.f / 64.f) - m * m;
    float rs = rsqrtf(var + 1e-5f);
    float* o = xn + (size_t)t * CC * PX + px;
    #pragma unroll
    for (int d = 0; d < DD; ++d) {
        o[d * PX]        = (pr[d * PX] - m) * rs * g[d]      + b[d];
        o[(d + DD) * PX] = (pi[d * PX] - m) * rs * g[d + DD] + b[d + DD];
    }
}

// ---------------- K2: 3x3 SAME conv 64->64, one (n,o) plane per block --------
__global__ __launch_bounds__(256) void k2_conv(
        const float* __restrict__ xn, const float* __restrict__ w,
        const float* __restrict__ bias, float* __restrict__ xs) {
    __shared__ float pl[66 * 66];
    int n = blockIdx.x >> 6;
    int o = blockIdx.x & 63;
    int tid = threadIdx.x;
    int wcol = tid & 63, grp = tid >> 6;
    int r0 = grp * 16;
    float acc[16];
    #pragma unroll
    for (int i = 0; i < 16; ++i) acc[i] = 0.f;
    const float* wb = w + (size_t)o * 64 * 9;
    for (int ic = 0; ic < 64; ++ic) {
        __syncthreads();
        const float* src = xn + ((size_t)n * 64 + ic) * PX;
        for (int idx = tid; idx < 66 * 66; idx += 256) {
            int rr = idx / 66, cc2 = idx - rr * 66;
            int ir = rr - 1, jc = cc2 - 1;
            float v = 0.f;
            if ((unsigned)ir < 64u && (unsigned)jc < 64u) v = src[ir * 64 + jc];
            pl[idx] = v;
        }
        __syncthreads();
        float wk[9];
        #pragma unroll
        for (int q = 0; q < 9; ++q) wk[q] = wb[ic * 9 + q];
        #pragma unroll
        for (int s = 0; s < 18; ++s) {
            int prow = r0 + s;
            float L = pl[prow * 66 + wcol];
            float M = pl[prow * 66 + wcol + 1];
            float R = pl[prow * 66 + wcol + 2];
            #pragma unroll
            for (int kh = 0; kh < 3; ++kh) {
                int os = s - kh;
                if (os >= 0 && os < 16)
                    acc[os] += wk[kh * 3] * L + wk[kh * 3 + 1] * M + wk[kh * 3 + 2] * R;
            }
        }
    }
    float bo = bias[o];
    float* dst = xs + ((size_t)n * 64 + o) * PX + wcol;
    #pragma unroll
    for (int i = 0; i < 16; ++i) dst[(r0 + i) * 64] = acc[i] + bo;
}

// ---------------- K3: per-(t,c) spatial mean -------------------------------
__global__ __launch_bounds__(256) void k3_mean(
        const float* __restrict__ xs, float* __restrict__ mean) {
    __shared__ float red[256];
    int plane = blockIdx.x;            // t*64 + c
    const float* p = xs + (size_t)plane * PX;
    float s = 0.f;
    for (int i = threadIdx.x; i < PX; i += 256) s += p[i];
    red[threadIdx.x] = s; __syncthreads();
    for (int st = 128; st > 0; st >>= 1) {
        if (threadIdx.x < st) red[threadIdx.x] += red[threadIdx.x + st];
        __syncthreads();
    }
    if (threadIdx.x == 0) mean[plane] = red[0] * (1.f / 4096.f);
}

// ---------------- K4: decay/forcing tables + flux scan ----------------------
__global__ __launch_bounds__(256) void k4_ops(
        const float* __restrict__ dt, const float* __restrict__ lam_re,
        const float* __restrict__ lam_im, const float* __restrict__ alpha,
        const float* __restrict__ wre, const float* __restrict__ wim,
        const float* __restrict__ mean, float* __restrict__ tabs,
        float* __restrict__ outflux) {
    int tid = threadIdx.x;
    for (int idx = tid; idx < 1024; idx += 256) {
        int t = idx >> 5, d = idx & 31;
        float x = lam_re[d];
        float sp = (x > 0.f) ? x + log1pf(expf(-x)) : log1pf(expf(x));
        float lr = -sp, li = lam_im[d];
        float dtv = dt[t];
        float er = expf(lr * dtv);
        float dr = er * cosf(li * dtv);
        float di = er * sinf(li * dtv);
        float den = lr * lr + li * li;
        float fr = ((dr - 1.f) * lr + di * li) / den;
        float fi = (di * lr - (dr - 1.f) * li) / den;
        tabs[idx] = dr; tabs[1024 + idx] = di;
        tabs[2048 + idx] = fr; tabs[3072 + idx] = fi;
    }
    if (tid < 32) {
        int d = tid;
        float a = 1.f / (1.f + expf(-alpha[d]));
        float yr = 0.f, yi = 0.f;
        for (int t = 0; t < 32; ++t) {
            float xr = 0.f, xi = 0.f;
            for (int k = 0; k < 32; ++k) {
                float mr = mean[t * 64 + k], mi = mean[t * 64 + 32 + k];
                float wr = wre[k * 32 + d], wi = wim[k * 32 + d];
                xr += mr * wr - mi * wi;
                xi += mr * wi + mi * wr;
            }
            yr = a * yr + xr; yi = a * yi + xi;
        }
        outflux[d] = yr; outflux[32 + d] = yi;
    }
}

// ---------------- K5: enc matmul + time scan + noise + dec matmul -----------
__global__ __launch_bounds__(256) void k5_seq(
        const float* __restrict__ xs,
        const float* __restrict__ enc_re, const float* __restrict__ enc_im,
        const float* __restrict__ dec_re, const float* __restrict__ dec_im,
        const float* __restrict__ tabs, const float* __restrict__ dt,
        const float* __restrict__ eps_re, const float* __restrict__ eps_im,
        float* __restrict__ xo) {
    __shared__ float xsl[8 * 64];
    __shared__ float uol[8 * 64];
    int tid = threadIdx.x;
    int lpx = tid >> 5, d = tid & 31;
    int pxbase = blockIdx.x * 8;
    float eR[32], eI[32], dR[32], dI[32];
    #pragma unroll
    for (int k = 0; k < 32; ++k) {
        eR[k] = enc_re[k * 32 + d]; eI[k] = enc_im[k * 32 + d];
        dR[k] = dec_re[k * 32 + d]; dI[k] = dec_im[k * 32 + d];
    }
    float Yr = 0.f, Yi = 0.f;
    for (int t = 0; t < TT; ++t) {
        for (int idx = tid; idx < 512; idx += 256) {
            int c = idx >> 3, p = idx & 7;
            xsl[p * 64 + c] = xs[((size_t)t * 64 + c) * PX + pxbase + p];
        }
        __syncthreads();
        float ur = 0.f, ui = 0.f;
        #pragma unroll
        for (int k = 0; k < 32; ++k) {
            float xr = xsl[lpx * 64 + k], xi = xsl[lpx * 64 + 32 + k];
            ur += xr * eR[k] - xi * eI[k];
            ui += xr * eI[k] + xi * eR[k];
        }
        float drr = tabs[t * 32 + d],        dii = tabs[1024 + t * 32 + d];
        float fr  = tabs[2048 + t * 32 + d], fi  = tabs[3072 + t * 32 + d];
        float usr = ur * fr - ui * fi;
        float usi = ur * fi + ui * fr;
        float nYr = drr * Yr - dii * Yi + usr;
        float nYi = drr * Yi + dii * Yr + usi;
        Yr = nYr; Yi = nYi;
        float s = 0.01f * sqrtf(dt[t]);
        size_t ei = ((size_t)t * PX + pxbase + lpx) * 32 + d;
        float epr = eps_re[ei], epi = eps_im[ei];
        float nr = Yr * epr - Yi * epi;
        float ni = Yr * epi + Yi * epr;
        uol[lpx * 64 + d]      = Yr + s * nr;
        uol[lpx * 64 + 32 + d] = Yi + s * ni;
        __syncthreads();
        float xr2 = 0.f, xi2 = 0.f;
        #pragma unroll
        for (int k = 0; k < 32; ++k) {
            float ar = uol[lpx * 64 + k], ai = uol[lpx * 64 + 32 + k];
            xr2 += ar * dR[k] - ai * dI[k];
            xi2 += ar * dI[k] + ai * dR[k];
        }
        size_t ob = ((size_t)t * PX + pxbase + lpx) * 64;
        xo[ob + d]      = xr2;
        xo[ob + 32 + d] = xi2;
    }
}

// ---------------- K0: prep — transpose+swizzle+bf16 the MoE weights ----------
// w1t[e][f][c'] where c' = (c&7) + 8*((c>>3)^(f&7)),  value = w1[e][c][f]
// w2t[e][n][f'] where f' = (f&7) + 8*((f>>3)^(n&7)),  value = w2[e][f][n]
__global__ __launch_bounds__(256) void k0_prep(
        const float* __restrict__ w1, const float* __restrict__ w2,
        unsigned short* __restrict__ w1t, unsigned short* __restrict__ w2t) {
    int gid = blockIdx.x * 256 + threadIdx.x;
    if (gid < 32768) {
        int idx = gid;                 // dest index in w1t
        int e = idx >> 13, r = idx & 8191;
        int f = r >> 6, p = r & 63;
        int c = (p & 7) + 8 * ((p >> 3) ^ (f & 7));
        w1t[idx] = f2b(w1[((size_t)e * 64 + c) * 128 + f]);
    } else {
        int idx = gid - 32768;         // dest index in w2t
        int e = idx >> 13, r = idx & 8191;
        int n = r >> 7, p = r & 127;
        int f = (p & 7) + 8 * ((p >> 3) ^ (n & 7));
        w2t[idx] = f2b(w2[((size_t)e * 128 + f) * 64 + n]);
    }
}

// ---------------- K6: LN2 + gated MoE MLP (bf16 MFMA) + residual write ------
// block = 64 tokens (one t, 64 consecutive px), 4 waves x 16-token MFMA slice.
__global__ __launch_bounds__(256, 2) void k6_moe(
        const float* __restrict__ xo,
        const float* __restrict__ g2, const float* __restrict__ b2ln,
        const float* __restrict__ wg,
        const unsigned short* __restrict__ w1t, const float* __restrict__ b1,
        const unsigned short* __restrict__ w2t, const float* __restrict__ b2m,
        const float* __restrict__ xre, const float* __restrict__ xim,
        float* __restrict__ out) {
    __shared__ __align__(16) float fld[64 * 65];          // LN2'd f (f32)
    __shared__ __align__(16) unsigned short fA[64 * 64];  // f bf16, chunk-swizzled
    __shared__ __align__(16) float hdl[64 * 65];          // union: H bf16 [64][128] swz / dl f32
    __shared__ __align__(16) unsigned short wst[16384];   // w1t(8192) + w2t(8192) bf16
    __shared__ float gate[64 * 4];
    __shared__ float stat[128];
    unsigned short* H = (unsigned short*)hdl;

    int tid = threadIdx.x;
    int lane = tid & 63;
    int wv = tid >> 6;
    int t = blockIdx.x >> 6;
    int px0 = (blockIdx.x & 63) * 64;

    // A: load 64 token rows (4096 f32) into padded fld
    {
        const float4* src = (const float4*)(xo + ((size_t)t * PX + px0) * 64);
        #pragma unroll
        for (int i = 0; i < 4; ++i) {
            int idx = i * 256 + tid;          // 1024 float4
            int tok = idx >> 4, c4 = idx & 15;
            float4 v = src[idx];
            float* dst = &fld[tok * 65 + c4 * 4];
            dst[0] = v.x; dst[1] = v.y; dst[2] = v.z; dst[3] = v.w;
        }
    }
    __syncthreads();
    // B1: LN2 stats (4 threads per token, shuffle-combine)
    {
        int tok = tid >> 2, q = tid & 3;
        float s = 0.f, ss = 0.f;
        #pragma unroll
        for (int i = 0; i < 16; ++i) {
            float v = fld[tok * 65 + q * 16 + i];
            s += v; ss += v * v;
        }
        s += __shfl_xor(s, 1); ss += __shfl_xor(ss, 1);
        s += __shfl_xor(s, 2); ss += __shfl_xor(ss, 2);
        if (q == 0) {
            float m = s * (1.f / 64.f);
            float var = ss * (1.f / 64.f) - m * m;
            stat[tok] = m; stat[64 + tok] = rsqrtf(var + 1e-5f);
        }
    }
    __syncthreads();
    // B2: normalize in place + write bf16 swizzled A tile (64 tok x 64 c = 4096)
    #pragma unroll
    for (int r = 0; r < 16; ++r) {
        int idx = r * 256 + tid;
        int tok = idx >> 6, c = idx & 63;
        float v = (fld[tok * 65 + c] - stat[tok]) * stat[64 + tok] * g2[c] + b2ln[c];
        fld[tok * 65 + c] = v;
        fA[tok * 64 + (c & 7) + 8 * ((c >> 3) ^ (tok & 7))] = f2b(v);
    }
    __syncthreads();
    // B3: gate logits (1 token x 1 expert per thread) + softmax
    {
        int tok = tid >> 2, e = tid & 3;
        float acc = 0.f;
        #pragma unroll 8
        for (int c = 0; c < 64; ++c) acc += fld[tok * 65 + c] * wg[c * 4 + e];
        gate[tok * 4 + e] = acc;
    }
    __syncthreads();
    if (tid < 64) {
        float l0 = gate[tid*4], l1 = gate[tid*4+1], l2 = gate[tid*4+2], l3 = gate[tid*4+3];
        float mx = fmaxf(fmaxf(l0, l1), fmaxf(l2, l3));
        float e0 = expf(l0-mx), e1 = expf(l1-mx), e2 = expf(l2-mx), e3 = expf(l3-mx);
        float inv = 1.f / (e0 + e1 + e2 + e3);
        gate[tid*4] = e0*inv; gate[tid*4+1] = e1*inv; gate[tid*4+2] = e2*inv; gate[tid*4+3] = e3*inv;
    }

    // MFMA geometry: wave wv owns tokens [wv*16, wv*16+16)
    int l15 = lane & 15, g = lane >> 4;
    int row0 = wv * 16 + l15;          // A-row / token for A frags
    int rowb = wv * 16 + g * 4;        // D-row base (+reg)

    // A fragments for GEMM1 (fA fixed for all experts)
    short8v a1[2];
    #pragma unroll
    for (int st = 0; st < 2; ++st) {
        int chunk = (st * 4 + g) ^ (row0 & 7);
        a1[st] = *(const short8v*)&fA[row0 * 64 + chunk * 8];
    }

    f32x4 dacc[4];
    #pragma unroll
    for (int i = 0; i < 4; ++i) dacc[i] = (f32x4)0.f;

    for (int e = 0; e < 4; ++e) {
        __syncthreads();   // wst/H reuse barrier
        // stage this expert's weights (linear, pre-swizzled in global)
        {
            const unsigned short* g1 = w1t + (size_t)e * 8192;
            const unsigned short* gw2 = w2t + (size_t)e * 8192;
            #pragma unroll
            for (int i = 0; i < 8; ++i) {
                int idx = i * 256 + tid;   // 2048 chunks of 8 ushort
                const unsigned short* src = (idx < 1024) ? (g1 + idx * 8)
                                                         : (gw2 + (idx - 1024) * 8);
                *(short8v*)&wst[idx * 8] = *(const short8v*)src;
            }
        }
        __syncthreads();
        // GEMM1: H[64x128] = gelu(f @ w1e + b1e)
        f32x4 h[8];
        #pragma unroll
        for (int i = 0; i < 8; ++i) h[i] = (f32x4)0.f;
        #pragma unroll
        for (int st = 0; st < 2; ++st) {
            #pragma unroll
            for (int nt = 0; nt < 8; ++nt) {
                int n = nt * 16 + l15;
                int chunk = (st * 4 + g) ^ (n & 7);
                short8v b = *(const short8v*)&wst[n * 64 + chunk * 8];
                h[nt] = __builtin_amdgcn_mfma_f32_16x16x32_bf16(a1[st], b, h[nt], 0, 0, 0);
            }
        }
        #pragma unroll
        for (int nt = 0; nt < 8; ++nt) {
            int f = nt * 16 + l15;
            float bb = b1[e * 128 + f];
            #pragma unroll
            for (int r = 0; r < 4; ++r) {
                int row = rowb + r;
                float v = gelu_tanh(h[nt][r] + bb);
                H[row * 128 + (f & 7) + 8 * ((f >> 3) ^ (row & 7))] = f2b(v);
            }
        }
        __syncthreads();
        // GEMM2: eo[64x64] = H @ w2e ; dacc += gate_e * (eo + b2e)
        f32x4 eo[4];
        #pragma unroll
        for (int i = 0; i < 4; ++i) eo[i] = (f32x4)0.f;
        #pragma unroll
        for (int st = 0; st < 4; ++st) {
            int chunkA = (st * 4 + g) ^ (row0 & 7);
            short8v a2 = *(const short8v*)&H[row0 * 128 + chunkA * 8];
            #pragma unroll
            for (int nt = 0; nt < 4; ++nt) {
                int n = nt * 16 + l15;
                int chunk = (st * 4 + g) ^ (n & 7);
                short8v b = *(const short8v*)&wst[8192 + n * 128 + chunk * 8];
                eo[nt] = __builtin_amdgcn_mfma_f32_16x16x32_bf16(a2, b, eo[nt], 0, 0, 0);
            }
        }
        #pragma unroll
        for (int nt = 0; nt < 4; ++nt) {
            int c = nt * 16 + l15;
            float bb = b2m[e * 64 + c];
            #pragma unroll
            for (int r = 0; r < 4; ++r) {
                float gt = gate[(rowb + r) * 4 + e];
                dacc[nt][r] += gt * (eo[nt][r] + bb);
            }
        }
    }
    __syncthreads();   // all H reads done; reuse hdl as f32 delta [64][65]
    float* dl = hdl;
    #pragma unroll
    for (int nt = 0; nt < 4; ++nt) {
        int c = nt * 16 + l15;
        #pragma unroll
        for (int r = 0; r < 4; ++r) dl[(rowb + r) * 65 + c] = dacc[nt][r];
    }
    __syncthreads();
    // final: out = x + (f + delta), channel-plane coalesced write
    #pragma unroll
    for (int r = 0; r < 16; ++r) {
        int idx = r * 256 + tid;           // 4096 = 64c x 64tok
        int c = idx >> 6, tok = idx & 63;
        float val = fld[tok * 65 + c] + dl[tok * 65 + c];
        size_t xi_ = ((size_t)t * 32 + (c & 31)) * PX + px0 + tok;
        float xv = (c < 32) ? xre[xi_] : xim[xi_];
        out[(size_t)(c < 32 ? 0 : 4194304) + xi_] = val + xv;
    }
}

extern "C" void kernel_launch(void* const* d_in, const int* in_sizes, int n_in,
                              void* d_out, int out_size, void* d_ws, size_t ws_size,
                              hipStream_t stream) {
    const float* xre   = (const float*)d_in[0];
    const float* xim   = (const float*)d_in[1];
    const float* dt    = (const float*)d_in[2];
    const float* epsre = (const float*)d_in[3];
    const float* epsim = (const float*)d_in[4];
    const float* ln1g  = (const float*)d_in[5];
    const float* ln1b  = (const float*)d_in[6];
    const float* ln2g  = (const float*)d_in[7];
    const float* ln2b  = (const float*)d_in[8];
    const float* convw = (const float*)d_in[9];
    const float* convb = (const float*)d_in[10];
    const float* encre = (const float*)d_in[11];
    const float* encim = (const float*)d_in[12];
    const float* decre = (const float*)d_in[13];
    const float* decim = (const float*)d_in[14];
    const float* lamre = (const float*)d_in[15];
    const float* lamim = (const float*)d_in[16];
    const float* alpha = (const float*)d_in[17];
    const float* fwre  = (const float*)d_in[18];
    const float* fwim  = (const float*)d_in[19];
    const float* wg    = (const float*)d_in[20];
    const float* w1    = (const float*)d_in[21];
    const float* b1    = (const float*)d_in[22];
    const float* w2    = (const float*)d_in[23];
    const float* b2    = (const float*)d_in[24];
    float* out = (float*)d_out;

    float* ws   = (float*)d_ws;
    float* xn   = ws;                   // 8388608 floats (also reused for xo)
    float* xs   = ws + 8388608;         // 8388608 floats
    float* mean = ws + 16777216;        // 2048 floats
    float* tabs = ws + 16779264;        // 4096 floats
    unsigned short* w1t = (unsigned short*)(ws + 16783360);   // 32768 bf16
    unsigned short* w2t = w1t + 32768;                        // 32768 bf16

    k0_prep<<<256, 256, 0, stream>>>(w1, w2, w1t, w2t);
    k1_ln1<<<512, 256, 0, stream>>>(xre, xim, ln1g, ln1b, xn);
    k2_conv<<<2048, 256, 0, stream>>>(xn, convw, convb, xs);
    k3_mean<<<2048, 256, 0, stream>>>(xs, mean);
    k4_ops<<<1, 256, 0, stream>>>(dt, lamre, lamim, alpha, fwre, fwim, mean,
                                  tabs, out + 8388608);
    k5_seq<<<512, 256, 0, stream>>>(xs, encre, encim, decre, decim, tabs, dt,
                                    epsre, epsim, xn);
    k6_moe<<<2048, 256, 0, stream>>>(xn, ln2g, ln2b, wg, w1t, b1, w2t, b2,
                                     xre, xim, out);
}

// Round 4
// 325.277 us; speedup vs baseline: 3.3324x; 2.2623x over previous
//
#include <hip/hip_runtime.h>
#include <math.h>

#define PX 4096   // 64*64
#define TT 32
#define DD 32
#define CC 64     // 2*D
#define PW 66     // padded width
#define PPX 4356  // 66*66

typedef __attribute__((ext_vector_type(8))) short short8v;
typedef __attribute__((ext_vector_type(4))) float f32x4;

__device__ __forceinline__ float gelu_tanh(float x) {
    float x3 = x * x * x;
    float z = 0.7978845608028654f * (x + 0.044715f * x3);
    return 0.5f * x * (1.0f + tanhf(z));
}

__device__ __forceinline__ unsigned short f2b(float x) {
    union { float f; unsigned u; } v; v.f = x;
    unsigned r = v.u + 0x7FFF + ((v.u >> 16) & 1);
    return (unsigned short)(r >> 16);
}

// ---------------- K1: LN1 (64ch) fused -> padded bf16 NHWC ------------------
__global__ __launch_bounds__(256) void k1_ln1(
        const float* __restrict__ xre, const float* __restrict__ xim,
        const float* __restrict__ g, const float* __restrict__ b,
        unsigned short* __restrict__ xpad) {
    int gid = blockIdx.x * 256 + threadIdx.x;   // t*4096 + px
    int t = gid >> 12, px = gid & 4095;
    int row = px >> 6, col = px & 63;
    const float* pr = xre + (size_t)t * DD * PX + px;
    const float* pi = xim + (size_t)t * DD * PX + px;
    float s = 0.f, ss = 0.f;
    #pragma unroll
    for (int d = 0; d < DD; ++d) {
        float vr = pr[d * PX], vi = pi[d * PX];
        s += vr + vi; ss += vr * vr + vi * vi;
    }
    float m = s * (1.f / 64.f);
    float var = ss * (1.f / 64.f) - m * m;
    float rs = rsqrtf(var + 1e-5f);
    unsigned short* o = xpad + ((size_t)t * PPX + (row + 1) * PW + (col + 1)) * 64;
    #pragma unroll
    for (int j = 0; j < 8; ++j) {
        short8v v8;
        #pragma unroll
        for (int dd = 0; dd < 8; ++dd) {
            int ch = j * 8 + dd;
            float v = (ch < 32) ? (pr[ch * PX] - m) * rs * g[ch] + b[ch]
                                : (pi[(ch - 32) * PX] - m) * rs * g[ch] + b[ch];
            v8[dd] = (short)f2b(v);
        }
        *(short8v*)&o[j * 8] = v8;
    }
}

// ---------------- KZ: zero the halo of xpad ---------------------------------
__global__ __launch_bounds__(256) void kz_halo(unsigned short* __restrict__ xpad) {
    int gid = blockIdx.x * 256 + threadIdx.x;
    if (gid >= 32 * 260) return;
    int im = gid / 260, h = gid % 260;
    int row, col;
    if (h < 66)       { row = 0;  col = h; }
    else if (h < 132) { row = 65; col = h - 66; }
    else { int hh = h - 132; row = 1 + (hh >> 1); col = (hh & 1) * 65; }
    unsigned short* p = xpad + ((size_t)im * PPX + row * PW + col) * 64;
    short8v z = (short8v)0;
    #pragma unroll
    for (int j = 0; j < 8; ++j) *(short8v*)&p[j * 8] = z;
}

// ---------------- K0: prep — bf16/transpose/swizzle MoE + conv weights ------
// w1t[e][f][c'], c' = (c&7)+8*((c>>3)^(f&7)), val = w1[e][c][f]
// w2t[e][n][f'], f' = (f&7)+8*((f>>3)^(n&7)), val = w2[e][f][n]
// w9t[tap][o][i'], i' = (i&7)+8*((i>>3)^(o&7)), val = convw[o][i][tap]
__global__ __launch_bounds__(256) void k0_prep(
        const float* __restrict__ w1, const float* __restrict__ w2,
        const float* __restrict__ convw,
        unsigned short* __restrict__ w1t, unsigned short* __restrict__ w2t,
        unsigned short* __restrict__ w9t) {
    int gid = blockIdx.x * 256 + threadIdx.x;
    if (gid < 32768) {
        int idx = gid;
        int e = idx >> 13, r = idx & 8191;
        int f = r >> 6, p = r & 63;
        int c = (p & 7) + 8 * ((p >> 3) ^ (f & 7));
        w1t[idx] = f2b(w1[((size_t)e * 64 + c) * 128 + f]);
    } else if (gid < 65536) {
        int idx = gid - 32768;
        int e = idx >> 13, r = idx & 8191;
        int n = r >> 7, p = r & 127;
        int f = (p & 7) + 8 * ((p >> 3) ^ (n & 7));
        w2t[idx] = f2b(w2[((size_t)e * 128 + f) * 64 + n]);
    } else if (gid < 65536 + 36864) {
        int idx = gid - 65536;
        int tap = idx >> 12, rem = idx & 4095;
        int n = rem >> 6, p = rem & 63;
        int k = (p & 7) + 8 * ((p >> 3) ^ (n & 7));
        w9t[idx] = f2b(convw[((size_t)n * 64 + k) * 9 + tap]);
    }
}

// ---------------- K2: 3x3 conv 64->64 as 9-tap implicit GEMM (bf16 MFMA) ----
// 512 blocks: logical = (image t, 4-row stripe). XCD-swizzled so each XCD
// owns 4 consecutive images (xpad L2-locality). Wave = 1 output row.
__global__ __launch_bounds__(256, 2) void k2_conv(
        const unsigned short* __restrict__ xpad,
        const unsigned short* __restrict__ w9t,
        const float* __restrict__ bias, float* __restrict__ xs) {
    __shared__ __align__(16) unsigned short wst[36864];   // 9 taps x 64oc x 64ic swz
    int tid = threadIdx.x;
    int bid = blockIdx.x;
    int lb = (bid & 7) * 64 + (bid >> 3);   // bijective (512 % 8 == 0)
    int t = lb >> 4, rg = lb & 15;
    int lane = tid & 63, wv = tid >> 6;
    int l15 = lane & 15, g = lane >> 4;
    // stage all 9 tap-weight matrices (pre-swizzled in global -> linear copy)
    #pragma unroll
    for (int i = 0; i < 18; ++i) {
        int idx = i * 256 + tid;
        *(short8v*)&wst[idx * 8] = *(const short8v*)&w9t[idx * 8];
    }
    __syncthreads();
    int r = rg * 4 + wv;                     // output row for this wave
    const unsigned short* xb = xpad + (size_t)t * PPX * 64;
    f32x4 acc[4][4];
    #pragma unroll
    for (int m = 0; m < 4; ++m)
        #pragma unroll
        for (int nt = 0; nt < 4; ++nt) acc[m][nt] = (f32x4)0.f;

    #pragma unroll
    for (int kh = 0; kh < 3; ++kh) {
        #pragma unroll
        for (int kw = 0; kw < 3; ++kw) {
            int tap = kh * 3 + kw;
            #pragma unroll
            for (int kc = 0; kc < 2; ++kc) {
                short8v a[4];
                #pragma unroll
                for (int m = 0; m < 4; ++m) {
                    int pcol = m * 16 + l15 + kw;
                    a[m] = *(const short8v*)&xb[((size_t)(r + kh) * PW + pcol) * 64 + kc * 32 + g * 8];
                }
                #pragma unroll
                for (int nt = 0; nt < 4; ++nt) {
                    int n = nt * 16 + l15;
                    short8v bf = *(const short8v*)&wst[tap * 4096 + n * 64 + ((kc * 4 + g) ^ (n & 7)) * 8];
                    #pragma unroll
                    for (int m = 0; m < 4; ++m)
                        acc[m][nt] = __builtin_amdgcn_mfma_f32_16x16x32_bf16(a[m], bf, acc[m][nt], 0, 0, 0);
                }
            }
        }
    }
    // epilogue: +bias, write NHWC f32
    float* dst = xs + ((size_t)t * PX + r * 64) * 64;
    #pragma unroll
    for (int nt = 0; nt < 4; ++nt) {
        float bo = bias[nt * 16 + l15];
        #pragma unroll
        for (int m = 0; m < 4; ++m) {
            #pragma unroll
            for (int reg = 0; reg < 4; ++reg) {
                int tok = m * 16 + g * 4 + reg;
                dst[(size_t)tok * 64 + nt * 16 + l15] = acc[m][nt][reg] + bo;
            }
        }
    }
}

// ---------------- K3: per-(t,c) spatial mean (NHWC input) -------------------
__global__ __launch_bounds__(256) void k3_mean(
        const float* __restrict__ xs, float* __restrict__ mean) {
    __shared__ f32x4 red[256];
    int t = blockIdx.x;
    int c4 = threadIdx.x & 15, q = threadIdx.x >> 4;
    const float* base = xs + (size_t)t * PX * 64 + c4 * 4;
    f32x4 s = (f32x4)0.f;
    for (int px = q; px < PX; px += 16)
        s += *(const f32x4*)&base[(size_t)px * 64];
    red[threadIdx.x] = s;
    __syncthreads();
    for (int st = 8; st > 0; st >>= 1) {
        if (q < st) red[q * 16 + c4] += red[(q + st) * 16 + c4];
        __syncthreads();
    }
    if (q == 0) {
        f32x4 v = red[c4];
        *(f32x4*)&mean[t * 64 + c4 * 4] =
            make_float4(v.x * (1.f/4096.f), v.y * (1.f/4096.f),
                        v.z * (1.f/4096.f), v.w * (1.f/4096.f)).x == 0.f && false
            ? v : v * (1.f / 4096.f);
    }
}

// ---------------- K4: decay/forcing tables + flux scan ----------------------
__global__ __launch_bounds__(256) void k4_ops(
        const float* __restrict__ dt, const float* __restrict__ lam_re,
        const float* __restrict__ lam_im, const float* __restrict__ alpha,
        const float* __restrict__ wre, const float* __restrict__ wim,
        const float* __restrict__ mean, float* __restrict__ tabs,
        float* __restrict__ outflux) {
    int tid = threadIdx.x;
    for (int idx = tid; idx < 1024; idx += 256) {
        int t = idx >> 5, d = idx & 31;
        float x = lam_re[d];
        float sp = (x > 0.f) ? x + log1pf(expf(-x)) : log1pf(expf(x));
        float lr = -sp, li = lam_im[d];
        float dtv = dt[t];
        float er = expf(lr * dtv);
        float dr = er * cosf(li * dtv);
        float di = er * sinf(li * dtv);
        float den = lr * lr + li * li;
        float fr = ((dr - 1.f) * lr + di * li) / den;
        float fi = (di * lr - (dr - 1.f) * li) / den;
        tabs[idx] = dr; tabs[1024 + idx] = di;
        tabs[2048 + idx] = fr; tabs[3072 + idx] = fi;
    }
    if (tid < 32) {
        int d = tid;
        float a = 1.f / (1.f + expf(-alpha[d]));
        float yr = 0.f, yi = 0.f;
        for (int t = 0; t < 32; ++t) {
            float xr = 0.f, xi = 0.f;
            for (int k = 0; k < 32; ++k) {
                float mr = mean[t * 64 + k], mi = mean[t * 64 + 32 + k];
                float wr = wre[k * 32 + d], wi = wim[k * 32 + d];
                xr += mr * wr - mi * wi;
                xi += mr * wi + mi * wr;
            }
            yr = a * yr + xr; yi = a * yi + xi;
        }
        outflux[d] = yr; outflux[32 + d] = yi;
    }
}

// ---------------- K5: enc matmul + time scan + noise + dec matmul -----------
__global__ __launch_bounds__(256) void k5_seq(
        const float* __restrict__ xs,
        const float* __restrict__ enc_re, const float* __restrict__ enc_im,
        const float* __restrict__ dec_re, const float* __restrict__ dec_im,
        const float* __restrict__ tabs, const float* __restrict__ dt,
        const float* __restrict__ eps_re, const float* __restrict__ eps_im,
        float* __restrict__ xo) {
    __shared__ float xsl[8 * 64];
    __shared__ float uol[8 * 64];
    int tid = threadIdx.x;
    int lpx = tid >> 5, d = tid & 31;
    int pxbase = blockIdx.x * 8;
    float eR[32], eI[32], dR[32], dI[32];
    #pragma unroll
    for (int k = 0; k < 32; ++k) {
        eR[k] = enc_re[k * 32 + d]; eI[k] = enc_im[k * 32 + d];
        dR[k] = dec_re[k * 32 + d]; dI[k] = dec_im[k * 32 + d];
    }
    float Yr = 0.f, Yi = 0.f;
    for (int t = 0; t < TT; ++t) {
        for (int idx = tid; idx < 512; idx += 256) {
            int p = idx >> 6, c = idx & 63;
            xsl[p * 64 + c] = xs[((size_t)t * PX + pxbase + p) * 64 + c];
        }
        __syncthreads();
        float ur = 0.f, ui = 0.f;
        #pragma unroll
        for (int k = 0; k < 32; ++k) {
            float xr = xsl[lpx * 64 + k], xi = xsl[lpx * 64 + 32 + k];
            ur += xr * eR[k] - xi * eI[k];
            ui += xr * eI[k] + xi * eR[k];
        }
        float drr = tabs[t * 32 + d],        dii = tabs[1024 + t * 32 + d];
        float fr  = tabs[2048 + t * 32 + d], fi  = tabs[3072 + t * 32 + d];
        float usr = ur * fr - ui * fi;
        float usi = ur * fi + ui * fr;
        float nYr = drr * Yr - dii * Yi + usr;
        float nYi = drr * Yi + dii * Yr + usi;
        Yr = nYr; Yi = nYi;
        float s = 0.01f * sqrtf(dt[t]);
        size_t ei = ((size_t)t * PX + pxbase + lpx) * 32 + d;
        float epr = eps_re[ei], epi = eps_im[ei];
        float nr = Yr * epr - Yi * epi;
        float ni = Yr * epi + Yi * epr;
        uol[lpx * 64 + d]      = Yr + s * nr;
        uol[lpx * 64 + 32 + d] = Yi + s * ni;
        __syncthreads();
        float xr2 = 0.f, xi2 = 0.f;
        #pragma unroll
        for (int k = 0; k < 32; ++k) {
            float ar = uol[lpx * 64 + k], ai = uol[lpx * 64 + 32 + k];
            xr2 += ar * dR[k] - ai * dI[k];
            xi2 += ar * dI[k] + ai * dR[k];
        }
        size_t ob = ((size_t)t * PX + pxbase + lpx) * 64;
        xo[ob + d]      = xr2;
        xo[ob + 32 + d] = xi2;
        __syncthreads();
    }
}

// ---------------- K6: LN2 + gated MoE MLP (bf16 MFMA) + residual write ------
__global__ __launch_bounds__(256, 2) void k6_moe(
        const float* __restrict__ xo,
        const float* __restrict__ g2, const float* __restrict__ b2ln,
        const float* __restrict__ wg,
        const unsigned short* __restrict__ w1t, const float* __restrict__ b1,
        const unsigned short* __restrict__ w2t, const float* __restrict__ b2m,
        const float* __restrict__ xre, const float* __restrict__ xim,
        float* __restrict__ out) {
    __shared__ __align__(16) float fld[64 * 65];
    __shared__ __align__(16) unsigned short fA[64 * 64];
    __shared__ __align__(16) float hdl[64 * 65];
    __shared__ __align__(16) unsigned short wst[16384];
    __shared__ float gate[64 * 4];
    __shared__ float stat[128];
    unsigned short* H = (unsigned short*)hdl;

    int tid = threadIdx.x;
    int lane = tid & 63;
    int wv = tid >> 6;
    int t = blockIdx.x >> 6;
    int px0 = (blockIdx.x & 63) * 64;

    {
        const float4* src = (const float4*)(xo + ((size_t)t * PX + px0) * 64);
        #pragma unroll
        for (int i = 0; i < 4; ++i) {
            int idx = i * 256 + tid;
            int tok = idx >> 4, c4 = idx & 15;
            float4 v = src[idx];
            float* dst = &fld[tok * 65 + c4 * 4];
            dst[0] = v.x; dst[1] = v.y; dst[2] = v.z; dst[3] = v.w;
        }
    }
    __syncthreads();
    {
        int tok = tid >> 2, q = tid & 3;
        float s = 0.f, ss = 0.f;
        #pragma unroll
        for (int i = 0; i < 16; ++i) {
            float v = fld[tok * 65 + q * 16 + i];
            s += v; ss += v * v;
        }
        s += __shfl_xor(s, 1); ss += __shfl_xor(ss, 1);
        s += __shfl_xor(s, 2); ss += __shfl_xor(ss, 2);
        if (q == 0) {
            float m = s * (1.f / 64.f);
            float var = ss * (1.f / 64.f) - m * m;
            stat[tok] = m; stat[64 + tok] = rsqrtf(var + 1e-5f);
        }
    }
    __syncthreads();
    #pragma unroll
    for (int r = 0; r < 16; ++r) {
        int idx = r * 256 + tid;
        int tok = idx >> 6, c = idx & 63;
        float v = (fld[tok * 65 + c] - stat[tok]) * stat[64 + tok] * g2[c] + b2ln[c];
        fld[tok * 65 + c] = v;
        fA[tok * 64 + (c & 7) + 8 * ((c >> 3) ^ (tok & 7))] = f2b(v);
    }
    __syncthreads();
    {
        int tok = tid >> 2, e = tid & 3;
        float acc = 0.f;
        #pragma unroll 8
        for (int c = 0; c < 64; ++c) acc += fld[tok * 65 + c] * wg[c * 4 + e];
        gate[tok * 4 + e] = acc;
    }
    __syncthreads();
    if (tid < 64) {
        float l0 = gate[tid*4], l1 = gate[tid*4+1], l2 = gate[tid*4+2], l3 = gate[tid*4+3];
        float mx = fmaxf(fmaxf(l0, l1), fmaxf(l2, l3));
        float e0 = expf(l0-mx), e1 = expf(l1-mx), e2 = expf(l2-mx), e3 = expf(l3-mx);
        float inv = 1.f / (e0 + e1 + e2 + e3);
        gate[tid*4] = e0*inv; gate[tid*4+1] = e1*inv; gate[tid*4+2] = e2*inv; gate[tid*4+3] = e3*inv;
    }

    int l15 = lane & 15, g = lane >> 4;
    int row0 = wv * 16 + l15;
    int rowb = wv * 16 + g * 4;

    short8v a1[2];
    #pragma unroll
    for (int st = 0; st < 2; ++st) {
        int chunk = (st * 4 + g) ^ (row0 & 7);
        a1[st] = *(const short8v*)&fA[row0 * 64 + chunk * 8];
    }

    f32x4 dacc[4];
    #pragma unroll
    for (int i = 0; i < 4; ++i) dacc[i] = (f32x4)0.f;

    for (int e = 0; e < 4; ++e) {
        __syncthreads();
        {
            const unsigned short* g1 = w1t + (size_t)e * 8192;
            const unsigned short* gw2 = w2t + (size_t)e * 8192;
            #pragma unroll
            for (int i = 0; i < 8; ++i) {
                int idx = i * 256 + tid;
                const unsigned short* src = (idx < 1024) ? (g1 + idx * 8)
                                                         : (gw2 + (idx - 1024) * 8);
                *(short8v*)&wst[idx * 8] = *(const short8v*)src;
            }
        }
        __syncthreads();
        f32x4 h[8];
        #pragma unroll
        for (int i = 0; i < 8; ++i) h[i] = (f32x4)0.f;
        #pragma unroll
        for (int st = 0; st < 2; ++st) {
            #pragma unroll
            for (int nt = 0; nt < 8; ++nt) {
                int n = nt * 16 + l15;
                int chunk = (st * 4 + g) ^ (n & 7);
                short8v b = *(const short8v*)&wst[n * 64 + chunk * 8];
                h[nt] = __builtin_amdgcn_mfma_f32_16x16x32_bf16(a1[st], b, h[nt], 0, 0, 0);
            }
        }
        #pragma unroll
        for (int nt = 0; nt < 8; ++nt) {
            int f = nt * 16 + l15;
            float bb = b1[e * 128 + f];
            #pragma unroll
            for (int r = 0; r < 4; ++r) {
                int row = rowb + r;
                float v = gelu_tanh(h[nt][r] + bb);
                H[row * 128 + (f & 7) + 8 * ((f >> 3) ^ (row & 7))] = f2b(v);
            }
        }
        __syncthreads();
        f32x4 eo[4];
        #pragma unroll
        for (int i = 0; i < 4; ++i) eo[i] = (f32x4)0.f;
        #pragma unroll
        for (int st = 0; st < 4; ++st) {
            int chunkA = (st * 4 + g) ^ (row0 & 7);
            short8v a2 = *(const short8v*)&H[row0 * 128 + chunkA * 8];
            #pragma unroll
            for (int nt = 0; nt < 4; ++nt) {
                int n = nt * 16 + l15;
                int chunk = (st * 4 + g) ^ (n & 7);
                short8v b = *(const short8v*)&wst[8192 + n * 128 + chunk * 8];
                eo[nt] = __builtin_amdgcn_mfma_f32_16x16x32_bf16(a2, b, eo[nt], 0, 0, 0);
            }
        }
        #pragma unroll
        for (int nt = 0; nt < 4; ++nt) {
            int c = nt * 16 + l15;
            float bb = b2m[e * 64 + c];
            #pragma unroll
            for (int r = 0; r < 4; ++r) {
                float gt = gate[(rowb + r) * 4 + e];
                dacc[nt][r] += gt * (eo[nt][r] + bb);
            }
        }
    }
    __syncthreads();
    float* dl = hdl;
    #pragma unroll
    for (int nt = 0; nt < 4; ++nt) {
        int c = nt * 16 + l15;
        #pragma unroll
        for (int r = 0; r < 4; ++r) dl[(rowb + r) * 65 + c] = dacc[nt][r];
    }
    __syncthreads();
    #pragma unroll
    for (int r = 0; r < 16; ++r) {
        int idx = r * 256 + tid;
        int c = idx >> 6, tok = idx & 63;
        float val = fld[tok * 65 + c] + dl[tok * 65 + c];
        size_t xi_ = ((size_t)t * 32 + (c & 31)) * PX + px0 + tok;
        float xv = (c < 32) ? xre[xi_] : xim[xi_];
        out[(size_t)(c < 32 ? 0 : 4194304) + xi_] = val + xv;
    }
}

extern "C" void kernel_launch(void* const* d_in, const int* in_sizes, int n_in,
                              void* d_out, int out_size, void* d_ws, size_t ws_size,
                              hipStream_t stream) {
    const float* xre   = (const float*)d_in[0];
    const float* xim   = (const float*)d_in[1];
    const float* dt    = (const float*)d_in[2];
    const float* epsre = (const float*)d_in[3];
    const float* epsim = (const float*)d_in[4];
    const float* ln1g  = (const float*)d_in[5];
    const float* ln1b  = (const float*)d_in[6];
    const float* ln2g  = (const float*)d_in[7];
    const float* ln2b  = (const float*)d_in[8];
    const float* convw = (const float*)d_in[9];
    const float* convb = (const float*)d_in[10];
    const float* encre = (const float*)d_in[11];
    const float* encim = (const float*)d_in[12];
    const float* decre = (const float*)d_in[13];
    const float* decim = (const float*)d_in[14];
    const float* lamre = (const float*)d_in[15];
    const float* lamim = (const float*)d_in[16];
    const float* alpha = (const float*)d_in[17];
    const float* fwre  = (const float*)d_in[18];
    const float* fwim  = (const float*)d_in[19];
    const float* wg    = (const float*)d_in[20];
    const float* w1    = (const float*)d_in[21];
    const float* b1    = (const float*)d_in[22];
    const float* w2    = (const float*)d_in[23];
    const float* b2    = (const float*)d_in[24];
    float* out = (float*)d_out;

    float* ws = (float*)d_ws;
    // region A [0, 8388608): xpad (bf16, 17.8MB) then reused as xo (f32, 32MB)
    unsigned short* xpad = (unsigned short*)ws;
    float* xo   = ws;
    float* xs   = ws + 8388608;         // NHWC f32 conv output
    float* mean = ws + 16777216;        // 2048 floats
    float* tabs = ws + 16779264;        // 4096 floats
    unsigned short* w1t = (unsigned short*)(ws + 16783360);   // 32768 bf16
    unsigned short* w2t = w1t + 32768;                        // 32768 bf16
    unsigned short* w9t = w2t + 32768;                        // 36864 bf16

    k0_prep<<<400, 256, 0, stream>>>(w1, w2, convw, w1t, w2t, w9t);
    kz_halo<<<33, 256, 0, stream>>>(xpad);
    k1_ln1<<<512, 256, 0, stream>>>(xre, xim, ln1g, ln1b, xpad);
    k2_conv<<<512, 256, 0, stream>>>(xpad, w9t, convb, xs);
    k3_mean<<<32, 256, 0, stream>>>(xs, mean);
    k4_ops<<<1, 256, 0, stream>>>(dt, lamre, lamim, alpha, fwre, fwim, mean,
                                  tabs, out + 8388608);
    k5_seq<<<512, 256, 0, stream>>>(xs, encre, encim, decre, decim, tabs, dt,
                                    epsre, epsim, xo);
    k6_moe<<<2048, 256, 0, stream>>>(xo, ln2g, ln2b, wg, w1t, b1, w2t, b2,
                                     xre, xim, out);
}

// Round 6
// 322.562 us; speedup vs baseline: 3.3604x; 1.0084x over previous
//
#include <hip/hip_runtime.h>
#include <math.h>

#define PX 4096   // 64*64
#define TT 32
#define DD 32
#define CC 64     // 2*D
#define PW 66     // padded width
#define PPX 4356  // 66*66

typedef __attribute__((ext_vector_type(8))) short short8v;
typedef __attribute__((ext_vector_type(4))) float f32x4;

__device__ __forceinline__ float gelu_fast(float x) {
    // gelu_tanh(x) == x * sigmoid(2z), z = 0.7978845608*(x + 0.044715 x^3)
    float u = x * x;
    float a = x * (1.5957691216057308f + 0.07135481627f * u);
    return x / (1.0f + __expf(-a));
}

__device__ __forceinline__ unsigned short f2b(float x) {
    union { float f; unsigned u; } v; v.f = x;
    unsigned r = v.u + 0x7FFF + ((v.u >> 16) & 1);
    return (unsigned short)(r >> 16);
}

// ---------------- K1: LN1 (64ch) fused -> padded bf16 NHWC ------------------
__global__ __launch_bounds__(256) void k1_ln1(
        const float* __restrict__ xre, const float* __restrict__ xim,
        const float* __restrict__ g, const float* __restrict__ b,
        unsigned short* __restrict__ xpad) {
    int gid = blockIdx.x * 256 + threadIdx.x;   // t*4096 + px
    int t = gid >> 12, px = gid & 4095;
    int row = px >> 6, col = px & 63;
    const float* pr = xre + (size_t)t * DD * PX + px;
    const float* pi = xim + (size_t)t * DD * PX + px;
    float s = 0.f, ss = 0.f;
    #pragma unroll
    for (int d = 0; d < DD; ++d) {
        float vr = pr[d * PX], vi = pi[d * PX];
        s += vr + vi; ss += vr * vr + vi * vi;
    }
    float m = s * (1.f / 64.f);
    float var = ss * (1.f / 64.f) - m * m;
    float rs = rsqrtf(var + 1e-5f);
    unsigned short* o = xpad + ((size_t)t * PPX + (row + 1) * PW + (col + 1)) * 64;
    #pragma unroll
    for (int j = 0; j < 8; ++j) {
        short8v v8;
        #pragma unroll
        for (int dd = 0; dd < 8; ++dd) {
            int ch = j * 8 + dd;
            float v = (ch < 32) ? (pr[ch * PX] - m) * rs * g[ch] + b[ch]
                                : (pi[(ch - 32) * PX] - m) * rs * g[ch] + b[ch];
            v8[dd] = (short)f2b(v);
        }
        *(short8v*)&o[j * 8] = v8;
    }
}

// ---------------- KZ: zero the halo of xpad ---------------------------------
__global__ __launch_bounds__(256) void kz_halo(unsigned short* __restrict__ xpad) {
    int gid = blockIdx.x * 256 + threadIdx.x;
    if (gid >= 32 * 260) return;
    int im = gid / 260, h = gid % 260;
    int row, col;
    if (h < 66)       { row = 0;  col = h; }
    else if (h < 132) { row = 65; col = h - 66; }
    else { int hh = h - 132; row = 1 + (hh >> 1); col = (hh & 1) * 65; }
    unsigned short* p = xpad + ((size_t)im * PPX + row * PW + col) * 64;
    short8v z = (short8v)0;
    #pragma unroll
    for (int j = 0; j < 8; ++j) *(short8v*)&p[j * 8] = z;
}

// ---------------- K0: prep — bf16/transpose/swizzle MoE + conv weights ------
__global__ __launch_bounds__(256) void k0_prep(
        const float* __restrict__ w1, const float* __restrict__ w2,
        const float* __restrict__ convw,
        unsigned short* __restrict__ w1t, unsigned short* __restrict__ w2t,
        unsigned short* __restrict__ w9t) {
    int gid = blockIdx.x * 256 + threadIdx.x;
    if (gid < 32768) {
        int idx = gid;
        int e = idx >> 13, r = idx & 8191;
        int f = r >> 6, p = r & 63;
        int c = (p & 7) + 8 * ((p >> 3) ^ (f & 7));
        w1t[idx] = f2b(w1[((size_t)e * 64 + c) * 128 + f]);
    } else if (gid < 65536) {
        int idx = gid - 32768;
        int e = idx >> 13, r = idx & 8191;
        int n = r >> 7, p = r & 127;
        int f = (p & 7) + 8 * ((p >> 3) ^ (n & 7));
        w2t[idx] = f2b(w2[((size_t)e * 128 + f) * 64 + n]);
    } else if (gid < 65536 + 36864) {
        int idx = gid - 65536;
        int tap = idx >> 12, rem = idx & 4095;
        int n = rem >> 6, p = rem & 63;
        int k = (p & 7) + 8 * ((p >> 3) ^ (n & 7));
        w9t[idx] = f2b(convw[((size_t)n * 64 + k) * 9 + tap]);
    }
}

// ---------------- K2: 3x3 conv 64->64 as 9-tap implicit GEMM (bf16 MFMA) ----
__global__ __launch_bounds__(256, 2) void k2_conv(
        const unsigned short* __restrict__ xpad,
        const unsigned short* __restrict__ w9t,
        const float* __restrict__ bias, float* __restrict__ xs) {
    __shared__ __align__(16) unsigned short wst[36864];   // 9 taps x 64oc x 64ic swz
    int tid = threadIdx.x;
    int bid = blockIdx.x;
    int lb = (bid & 7) * 64 + (bid >> 3);   // bijective (512 % 8 == 0)
    int t = lb >> 4, rg = lb & 15;
    int lane = tid & 63, wv = tid >> 6;
    int l15 = lane & 15, g = lane >> 4;
    #pragma unroll
    for (int i = 0; i < 18; ++i) {
        int idx = i * 256 + tid;
        *(short8v*)&wst[idx * 8] = *(const short8v*)&w9t[idx * 8];
    }
    __syncthreads();
    int r = rg * 4 + wv;
    const unsigned short* xb = xpad + (size_t)t * PPX * 64;
    f32x4 acc[4][4];
    #pragma unroll
    for (int m = 0; m < 4; ++m)
        #pragma unroll
        for (int nt = 0; nt < 4; ++nt) acc[m][nt] = (f32x4)0.f;

    #pragma unroll
    for (int kh = 0; kh < 3; ++kh) {
        #pragma unroll
        for (int kw = 0; kw < 3; ++kw) {
            int tap = kh * 3 + kw;
            #pragma unroll
            for (int kc = 0; kc < 2; ++kc) {
                short8v a[4];
                #pragma unroll
                for (int m = 0; m < 4; ++m) {
                    int pcol = m * 16 + l15 + kw;
                    a[m] = *(const short8v*)&xb[((size_t)(r + kh) * PW + pcol) * 64 + kc * 32 + g * 8];
                }
                #pragma unroll
                for (int nt = 0; nt < 4; ++nt) {
                    int n = nt * 16 + l15;
                    short8v bf = *(const short8v*)&wst[tap * 4096 + n * 64 + ((kc * 4 + g) ^ (n & 7)) * 8];
                    #pragma unroll
                    for (int m = 0; m < 4; ++m)
                        acc[m][nt] = __builtin_amdgcn_mfma_f32_16x16x32_bf16(a[m], bf, acc[m][nt], 0, 0, 0);
                }
            }
        }
    }
    float* dst = xs + ((size_t)t * PX + r * 64) * 64;
    #pragma unroll
    for (int nt = 0; nt < 4; ++nt) {
        float bo = bias[nt * 16 + l15];
        #pragma unroll
        for (int m = 0; m < 4; ++m) {
            #pragma unroll
            for (int reg = 0; reg < 4; ++reg) {
                int tok = m * 16 + g * 4 + reg;
                dst[(size_t)tok * 64 + nt * 16 + l15] = acc[m][nt][reg] + bo;
            }
        }
    }
}

// ---------------- K3: per-(t,c) spatial mean (NHWC input) -------------------
__global__ __launch_bounds__(256) void k3_mean(
        const float* __restrict__ xs, float* __restrict__ mean) {
    __shared__ f32x4 red[256];
    int t = blockIdx.x;
    int c4 = threadIdx.x & 15, q = threadIdx.x >> 4;
    const float* base = xs + (size_t)t * PX * 64 + c4 * 4;
    f32x4 s = (f32x4)0.f;
    for (int px = q; px < PX; px += 16)
        s += *(const f32x4*)&base[(size_t)px * 64];
    red[threadIdx.x] = s;
    __syncthreads();
    for (int st = 8; st > 0; st >>= 1) {
        if (q < st) red[q * 16 + c4] += red[(q + st) * 16 + c4];
        __syncthreads();
    }
    if (q == 0) {
        f32x4 v = red[c4] * (1.f / 4096.f);
        *(f32x4*)&mean[t * 64 + c4 * 4] = v;
    }
}

// ---------------- K4: decay/forcing tables + flux scan ----------------------
__global__ __launch_bounds__(256) void k4_ops(
        const float* __restrict__ dt, const float* __restrict__ lam_re,
        const float* __restrict__ lam_im, const float* __restrict__ alpha,
        const float* __restrict__ wre, const float* __restrict__ wim,
        const float* __restrict__ mean, float* __restrict__ tabs,
        float* __restrict__ outflux) {
    int tid = threadIdx.x;
    for (int idx = tid; idx < 1024; idx += 256) {
        int t = idx >> 5, d = idx & 31;
        float x = lam_re[d];
        float sp = (x > 0.f) ? x + log1pf(expf(-x)) : log1pf(expf(x));
        float lr = -sp, li = lam_im[d];
        float dtv = dt[t];
        float er = expf(lr * dtv);
        float dr = er * cosf(li * dtv);
        float di = er * sinf(li * dtv);
        float den = lr * lr + li * li;
        float fr = ((dr - 1.f) * lr + di * li) / den;
        float fi = (di * lr - (dr - 1.f) * li) / den;
        tabs[idx] = dr; tabs[1024 + idx] = di;
        tabs[2048 + idx] = fr; tabs[3072 + idx] = fi;
    }
    if (tid < 32) {
        int d = tid;
        float a = 1.f / (1.f + expf(-alpha[d]));
        float yr = 0.f, yi = 0.f;
        for (int t = 0; t < 32; ++t) {
            float xr = 0.f, xi = 0.f;
            for (int k = 0; k < 32; ++k) {
                float mr = mean[t * 64 + k], mi = mean[t * 64 + 32 + k];
                float wr = wre[k * 32 + d], wi = wim[k * 32 + d];
                xr += mr * wr - mi * wi;
                xi += mr * wi + mi * wr;
            }
            yr = a * yr + xr; yi = a * yi + xi;
        }
        outflux[d] = yr; outflux[32 + d] = yi;
    }
}

// ---------------- K5: enc matmul + time scan + noise + dec matmul -----------
__global__ __launch_bounds__(256) void k5_seq(
        const float* __restrict__ xs,
        const float* __restrict__ enc_re, const float* __restrict__ enc_im,
        const float* __restrict__ dec_re, const float* __restrict__ dec_im,
        const float* __restrict__ tabs, const float* __restrict__ dt,
        const float* __restrict__ eps_re, const float* __restrict__ eps_im,
        float* __restrict__ xo) {
    __shared__ float xsl[8 * 64];
    __shared__ float uol[8 * 64];
    int tid = threadIdx.x;
    int lpx = tid >> 5, d = tid & 31;
    int pxbase = blockIdx.x * 8;
    float eR[32], eI[32], dR[32], dI[32];
    #pragma unroll
    for (int k = 0; k < 32; ++k) {
        eR[k] = enc_re[k * 32 + d]; eI[k] = enc_im[k * 32 + d];
        dR[k] = dec_re[k * 32 + d]; dI[k] = dec_im[k * 32 + d];
    }
    float Yr = 0.f, Yi = 0.f;
    for (int t = 0; t < TT; ++t) {
        for (int idx = tid; idx < 512; idx += 256) {
            int p = idx >> 6, c = idx & 63;
            xsl[p * 64 + c] = xs[((size_t)t * PX + pxbase + p) * 64 + c];
        }
        __syncthreads();
        float ur = 0.f, ui = 0.f;
        #pragma unroll
        for (int k = 0; k < 32; ++k) {
            float xr = xsl[lpx * 64 + k], xi = xsl[lpx * 64 + 32 + k];
            ur += xr * eR[k] - xi * eI[k];
            ui += xr * eI[k] + xi * eR[k];
        }
        float drr = tabs[t * 32 + d],        dii = tabs[1024 + t * 32 + d];
        float fr  = tabs[2048 + t * 32 + d], fi  = tabs[3072 + t * 32 + d];
        float usr = ur * fr - ui * fi;
        float usi = ur * fi + ui * fr;
        float nYr = drr * Yr - dii * Yi + usr;
        float nYi = drr * Yi + dii * Yr + usi;
        Yr = nYr; Yi = nYi;
        float s = 0.01f * sqrtf(dt[t]);
        size_t ei = ((size_t)t * PX + pxbase + lpx) * 32 + d;
        float epr = eps_re[ei], epi = eps_im[ei];
        float nr = Yr * epr - Yi * epi;
        float ni = Yr * epi + Yi * epr;
        uol[lpx * 64 + d]      = Yr + s * nr;
        uol[lpx * 64 + 32 + d] = Yi + s * ni;
        __syncthreads();
        float xr2 = 0.f, xi2 = 0.f;
        #pragma unroll
        for (int k = 0; k < 32; ++k) {
            float ar = uol[lpx * 64 + k], ai = uol[lpx * 64 + 32 + k];
            xr2 += ar * dR[k] - ai * dI[k];
            xi2 += ar * dI[k] + ai * dR[k];
        }
        size_t ob = ((size_t)t * PX + pxbase + lpx) * 64;
        xo[ob + d]      = xr2;
        xo[ob + 32 + d] = xi2;
        __syncthreads();
    }
}

// ---------------- K6: LN2 + gated MoE MLP (bf16 MFMA) + residual write ------
// R4-proven structure; ONLY change: gelu_tanh -> gelu_fast (x*sigmoid(2z)).
__global__ __launch_bounds__(256, 2) void k6_moe(
        const float* __restrict__ xo,
        const float* __restrict__ g2, const float* __restrict__ b2ln,
        const float* __restrict__ wg,
        const unsigned short* __restrict__ w1t, const float* __restrict__ b1,
        const unsigned short* __restrict__ w2t, const float* __restrict__ b2m,
        const float* __restrict__ xre, const float* __restrict__ xim,
        float* __restrict__ out) {
    __shared__ __align__(16) float fld[64 * 65];
    __shared__ __align__(16) unsigned short fA[64 * 64];
    __shared__ __align__(16) float hdl[64 * 65];
    __shared__ __align__(16) unsigned short wst[16384];
    __shared__ float gate[64 * 4];
    __shared__ float stat[128];
    unsigned short* H = (unsigned short*)hdl;

    int tid = threadIdx.x;
    int lane = tid & 63;
    int wv = tid >> 6;
    int t = blockIdx.x >> 6;
    int px0 = (blockIdx.x & 63) * 64;

    {
        const float4* src = (const float4*)(xo + ((size_t)t * PX + px0) * 64);
        #pragma unroll
        for (int i = 0; i < 4; ++i) {
            int idx = i * 256 + tid;
            int tok = idx >> 4, c4 = idx & 15;
            float4 v = src[idx];
            float* dst = &fld[tok * 65 + c4 * 4];
            dst[0] = v.x; dst[1] = v.y; dst[2] = v.z; dst[3] = v.w;
        }
    }
    __syncthreads();
    {
        int tok = tid >> 2, q = tid & 3;
        float s = 0.f, ss = 0.f;
        #pragma unroll
        for (int i = 0; i < 16; ++i) {
            float v = fld[tok * 65 + q * 16 + i];
            s += v; ss += v * v;
        }
        s += __shfl_xor(s, 1); ss += __shfl_xor(ss, 1);
        s += __shfl_xor(s, 2); ss += __shfl_xor(ss, 2);
        if (q == 0) {
            float m = s * (1.f / 64.f);
            float var = ss * (1.f / 64.f) - m * m;
            stat[tok] = m; stat[64 + tok] = rsqrtf(var + 1e-5f);
        }
    }
    __syncthreads();
    #pragma unroll
    for (int r = 0; r < 16; ++r) {
        int idx = r * 256 + tid;
        int tok = idx >> 6, c = idx & 63;
        float v = (fld[tok * 65 + c] - stat[tok]) * stat[64 + tok] * g2[c] + b2ln[c];
        fld[tok * 65 + c] = v;
        fA[tok * 64 + (c & 7) + 8 * ((c >> 3) ^ (tok & 7))] = f2b(v);
    }
    __syncthreads();
    {
        int tok = tid >> 2, e = tid & 3;
        float acc = 0.f;
        #pragma unroll 8
        for (int c = 0; c < 64; ++c) acc += fld[tok * 65 + c] * wg[c * 4 + e];
        gate[tok * 4 + e] = acc;
    }
    __syncthreads();
    if (tid < 64) {
        float l0 = gate[tid*4], l1 = gate[tid*4+1], l2 = gate[tid*4+2], l3 = gate[tid*4+3];
        float mx = fmaxf(fmaxf(l0, l1), fmaxf(l2, l3));
        float e0 = expf(l0-mx), e1 = expf(l1-mx), e2 = expf(l2-mx), e3 = expf(l3-mx);
        float inv = 1.f / (e0 + e1 + e2 + e3);
        gate[tid*4] = e0*inv; gate[tid*4+1] = e1*inv; gate[tid*4+2] = e2*inv; gate[tid*4+3] = e3*inv;
    }

    int l15 = lane & 15, g = lane >> 4;
    int row0 = wv * 16 + l15;
    int rowb = wv * 16 + g * 4;

    short8v a1[2];
    #pragma unroll
    for (int st = 0; st < 2; ++st) {
        int chunk = (st * 4 + g) ^ (row0 & 7);
        a1[st] = *(const short8v*)&fA[row0 * 64 + chunk * 8];
    }

    f32x4 dacc[4];
    #pragma unroll
    for (int i = 0; i < 4; ++i) dacc[i] = (f32x4)0.f;

    for (int e = 0; e < 4; ++e) {
        __syncthreads();
        {
            const unsigned short* g1 = w1t + (size_t)e * 8192;
            const unsigned short* gw2 = w2t + (size_t)e * 8192;
            #pragma unroll
            for (int i = 0; i < 8; ++i) {
                int idx = i * 256 + tid;
                const unsigned short* src = (idx < 1024) ? (g1 + idx * 8)
                                                         : (gw2 + (idx - 1024) * 8);
                *(short8v*)&wst[idx * 8] = *(const short8v*)src;
            }
        }
        __syncthreads();
        f32x4 h[8];
        #pragma unroll
        for (int i = 0; i < 8; ++i) h[i] = (f32x4)0.f;
        #pragma unroll
        for (int st = 0; st < 2; ++st) {
            #pragma unroll
            for (int nt = 0; nt < 8; ++nt) {
                int n = nt * 16 + l15;
                int chunk = (st * 4 + g) ^ (n & 7);
                short8v b = *(const short8v*)&wst[n * 64 + chunk * 8];
                h[nt] = __builtin_amdgcn_mfma_f32_16x16x32_bf16(a1[st], b, h[nt], 0, 0, 0);
            }
        }
        #pragma unroll
        for (int nt = 0; nt < 8; ++nt) {
            int f = nt * 16 + l15;
            float bb = b1[e * 128 + f];
            #pragma unroll
            for (int r = 0; r < 4; ++r) {
                int row = rowb + r;
                float v = gelu_fast(h[nt][r] + bb);
                H[row * 128 + (f & 7) + 8 * ((f >> 3) ^ (row & 7))] = f2b(v);
            }
        }
        __syncthreads();
        f32x4 eo[4];
        #pragma unroll
        for (int i = 0; i < 4; ++i) eo[i] = (f32x4)0.f;
        #pragma unroll
        for (int st = 0; st < 4; ++st) {
            int chunkA = (st * 4 + g) ^ (row0 & 7);
            short8v a2 = *(const short8v*)&H[row0 * 128 + chunkA * 8];
            #pragma unroll
            for (int nt = 0; nt < 4; ++nt) {
                int n = nt * 16 + l15;
                int chunk = (st * 4 + g) ^ (n & 7);
                short8v b = *(const short8v*)&wst[8192 + n * 128 + chunk * 8];
                eo[nt] = __builtin_amdgcn_mfma_f32_16x16x32_bf16(a2, b, eo[nt], 0, 0, 0);
            }
        }
        #pragma unroll
        for (int nt = 0; nt < 4; ++nt) {
            int c = nt * 16 + l15;
            float bb = b2m[e * 64 + c];
            #pragma unroll
            for (int r = 0; r < 4; ++r) {
                float gt = gate[(rowb + r) * 4 + e];
                dacc[nt][r] += gt * (eo[nt][r] + bb);
            }
        }
    }
    __syncthreads();
    float* dl = hdl;
    #pragma unroll
    for (int nt = 0; nt < 4; ++nt) {
        int c = nt * 16 + l15;
        #pragma unroll
        for (int r = 0; r < 4; ++r) dl[(rowb + r) * 65 + c] = dacc[nt][r];
    }
    __syncthreads();
    #pragma unroll
    for (int r = 0; r < 16; ++r) {
        int idx = r * 256 + tid;
        int c = idx >> 6, tok = idx & 63;
        float val = fld[tok * 65 + c] + dl[tok * 65 + c];
        size_t xi_ = ((size_t)t * 32 + (c & 31)) * PX + px0 + tok;
        float xv = (c < 32) ? xre[xi_] : xim[xi_];
        out[(size_t)(c < 32 ? 0 : 4194304) + xi_] = val + xv;
    }
}

extern "C" void kernel_launch(void* const* d_in, const int* in_sizes, int n_in,
                              void* d_out, int out_size, void* d_ws, size_t ws_size,
                              hipStream_t stream) {
    const float* xre   = (const float*)d_in[0];
    const float* xim   = (const float*)d_in[1];
    const float* dt    = (const float*)d_in[2];
    const float* epsre = (const float*)d_in[3];
    const float* epsim = (const float*)d_in[4];
    const float* ln1g  = (const float*)d_in[5];
    const float* ln1b  = (const float*)d_in[6];
    const float* ln2g  = (const float*)d_in[7];
    const float* ln2b  = (const float*)d_in[8];
    const float* convw = (const float*)d_in[9];
    const float* convb = (const float*)d_in[10];
    const float* encre = (const float*)d_in[11];
    const float* encim = (const float*)d_in[12];
    const float* decre = (const float*)d_in[13];
    const float* decim = (const float*)d_in[14];
    const float* lamre = (const float*)d_in[15];
    const float* lamim = (const float*)d_in[16];
    const float* alpha = (const float*)d_in[17];
    const float* fwre  = (const float*)d_in[18];
    const float* fwim  = (const float*)d_in[19];
    const float* wg    = (const float*)d_in[20];
    const float* w1    = (const float*)d_in[21];
    const float* b1    = (const float*)d_in[22];
    const float* w2    = (const float*)d_in[23];
    const float* b2    = (const float*)d_in[24];
    float* out = (float*)d_out;

    float* ws = (float*)d_ws;
    unsigned short* xpad = (unsigned short*)ws;   // region A: xpad bf16 then xo f32
    float* xo   = ws;
    float* xs   = ws + 8388608;         // NHWC f32 conv output
    float* mean = ws + 16777216;
    float* tabs = ws + 16779264;
    unsigned short* w1t = (unsigned short*)(ws + 16783360);
    unsigned short* w2t = w1t + 32768;
    unsigned short* w9t = w2t + 32768;

    k0_prep<<<400, 256, 0, stream>>>(w1, w2, convw, w1t, w2t, w9t);
    kz_halo<<<33, 256, 0, stream>>>(xpad);
    k1_ln1<<<512, 256, 0, stream>>>(xre, xim, ln1g, ln1b, xpad);
    k2_conv<<<512, 256, 0, stream>>>(xpad, w9t, convb, xs);
    k3_mean<<<32, 256, 0, stream>>>(xs, mean);
    k4_ops<<<1, 256, 0, stream>>>(dt, lamre, lamim, alpha, fwre, fwim, mean,
                                  tabs, out + 8388608);
    k5_seq<<<512, 256, 0, stream>>>(xs, encre, encim, decre, decim, tabs, dt,
                                    epsre, epsim, xo);
    k6_moe<<<2048, 256, 0, stream>>>(xo, ln2g, ln2b, wg, w1t, b1, w2t, b2,
                                     xre, xim, out);
}

// Round 7
// 314.533 us; speedup vs baseline: 3.4462x; 1.0255x over previous
//
#include <hip/hip_runtime.h>
#include <math.h>

#define PX 4096   // 64*64
#define TT 32
#define DD 32
#define CC 64     // 2*D
#define PW 66     // padded width
#define PPX 4356  // 66*66

typedef __attribute__((ext_vector_type(8))) short short8v;
typedef __attribute__((ext_vector_type(4))) float f32x4;

__device__ __forceinline__ float gelu_fast(float x) {
    // gelu_tanh(x) == x * sigmoid(2z), z = 0.7978845608*(x + 0.044715 x^3)
    float u = x * x;
    float a = x * (1.5957691216057308f + 0.07135481627f * u);
    return x / (1.0f + __expf(-a));
}

__device__ __forceinline__ unsigned short f2b(float x) {
    union { float f; unsigned u; } v; v.f = x;
    unsigned r = v.u + 0x7FFF + ((v.u >> 16) & 1);
    return (unsigned short)(r >> 16);
}

// ---------------- K1: LN1 (64ch) fused -> padded bf16 NHWC ------------------
__global__ __launch_bounds__(256) void k1_ln1(
        const float* __restrict__ xre, const float* __restrict__ xim,
        const float* __restrict__ g, const float* __restrict__ b,
        unsigned short* __restrict__ xpad) {
    int gid = blockIdx.x * 256 + threadIdx.x;   // t*4096 + px
    int t = gid >> 12, px = gid & 4095;
    int row = px >> 6, col = px & 63;
    const float* pr = xre + (size_t)t * DD * PX + px;
    const float* pi = xim + (size_t)t * DD * PX + px;
    float s = 0.f, ss = 0.f;
    #pragma unroll
    for (int d = 0; d < DD; ++d) {
        float vr = pr[d * PX], vi = pi[d * PX];
        s += vr + vi; ss += vr * vr + vi * vi;
    }
    float m = s * (1.f / 64.f);
    float var = ss * (1.f / 64.f) - m * m;
    float rs = rsqrtf(var + 1e-5f);
    unsigned short* o = xpad + ((size_t)t * PPX + (row + 1) * PW + (col + 1)) * 64;
    #pragma unroll
    for (int j = 0; j < 8; ++j) {
        short8v v8;
        #pragma unroll
        for (int dd = 0; dd < 8; ++dd) {
            int ch = j * 8 + dd;
            float v = (ch < 32) ? (pr[ch * PX] - m) * rs * g[ch] + b[ch]
                                : (pi[(ch - 32) * PX] - m) * rs * g[ch] + b[ch];
            v8[dd] = (short)f2b(v);
        }
        *(short8v*)&o[j * 8] = v8;
    }
}

// ---------------- KZ: zero the halo of xpad ---------------------------------
__global__ __launch_bounds__(256) void kz_halo(unsigned short* __restrict__ xpad) {
    int gid = blockIdx.x * 256 + threadIdx.x;
    if (gid >= 32 * 260) return;
    int im = gid / 260, h = gid % 260;
    int row, col;
    if (h < 66)       { row = 0;  col = h; }
    else if (h < 132) { row = 65; col = h - 66; }
    else { int hh = h - 132; row = 1 + (hh >> 1); col = (hh & 1) * 65; }
    unsigned short* p = xpad + ((size_t)im * PPX + row * PW + col) * 64;
    short8v z = (short8v)0;
    #pragma unroll
    for (int j = 0; j < 8; ++j) *(short8v*)&p[j * 8] = z;
}

// ---------------- K0: prep — bf16/transpose/swizzle MoE + conv weights ------
__global__ __launch_bounds__(256) void k0_prep(
        const float* __restrict__ w1, const float* __restrict__ w2,
        const float* __restrict__ convw,
        unsigned short* __restrict__ w1t, unsigned short* __restrict__ w2t,
        unsigned short* __restrict__ w9t) {
    int gid = blockIdx.x * 256 + threadIdx.x;
    if (gid < 32768) {
        int idx = gid;
        int e = idx >> 13, r = idx & 8191;
        int f = r >> 6, p = r & 63;
        int c = (p & 7) + 8 * ((p >> 3) ^ (f & 7));
        w1t[idx] = f2b(w1[((size_t)e * 64 + c) * 128 + f]);
    } else if (gid < 65536) {
        int idx = gid - 32768;
        int e = idx >> 13, r = idx & 8191;
        int n = r >> 7, p = r & 127;
        int f = (p & 7) + 8 * ((p >> 3) ^ (n & 7));
        w2t[idx] = f2b(w2[((size_t)e * 128 + f) * 64 + n]);
    } else if (gid < 65536 + 36864) {
        int idx = gid - 65536;
        int tap = idx >> 12, rem = idx & 4095;
        int n = rem >> 6, p = rem & 63;
        int k = (p & 7) + 8 * ((p >> 3) ^ (n & 7));
        w9t[idx] = f2b(convw[((size_t)n * 64 + k) * 9 + tap]);
    }
}

// ---------------- K2: 3x3 conv 64->64 as 9-tap implicit GEMM (bf16 MFMA) ----
__global__ __launch_bounds__(256, 2) void k2_conv(
        const unsigned short* __restrict__ xpad,
        const unsigned short* __restrict__ w9t,
        const float* __restrict__ bias, float* __restrict__ xs) {
    __shared__ __align__(16) unsigned short wst[36864];   // 9 taps x 64oc x 64ic swz
    int tid = threadIdx.x;
    int bid = blockIdx.x;
    int lb = (bid & 7) * 64 + (bid >> 3);   // bijective (512 % 8 == 0)
    int t = lb >> 4, rg = lb & 15;
    int lane = tid & 63, wv = tid >> 6;
    int l15 = lane & 15, g = lane >> 4;
    #pragma unroll
    for (int i = 0; i < 18; ++i) {
        int idx = i * 256 + tid;
        *(short8v*)&wst[idx * 8] = *(const short8v*)&w9t[idx * 8];
    }
    __syncthreads();
    int r = rg * 4 + wv;
    const unsigned short* xb = xpad + (size_t)t * PPX * 64;
    f32x4 acc[4][4];
    #pragma unroll
    for (int m = 0; m < 4; ++m)
        #pragma unroll
        for (int nt = 0; nt < 4; ++nt) acc[m][nt] = (f32x4)0.f;

    #pragma unroll
    for (int kh = 0; kh < 3; ++kh) {
        #pragma unroll
        for (int kw = 0; kw < 3; ++kw) {
            int tap = kh * 3 + kw;
            #pragma unroll
            for (int kc = 0; kc < 2; ++kc) {
                short8v a[4];
                #pragma unroll
                for (int m = 0; m < 4; ++m) {
                    int pcol = m * 16 + l15 + kw;
                    a[m] = *(const short8v*)&xb[((size_t)(r + kh) * PW + pcol) * 64 + kc * 32 + g * 8];
                }
                #pragma unroll
                for (int nt = 0; nt < 4; ++nt) {
                    int n = nt * 16 + l15;
                    short8v bf = *(const short8v*)&wst[tap * 4096 + n * 64 + ((kc * 4 + g) ^ (n & 7)) * 8];
                    #pragma unroll
                    for (int m = 0; m < 4; ++m)
                        acc[m][nt] = __builtin_amdgcn_mfma_f32_16x16x32_bf16(a[m], bf, acc[m][nt], 0, 0, 0);
                }
            }
        }
    }
    float* dst = xs + ((size_t)t * PX + r * 64) * 64;
    #pragma unroll
    for (int nt = 0; nt < 4; ++nt) {
        float bo = bias[nt * 16 + l15];
        #pragma unroll
        for (int m = 0; m < 4; ++m) {
            #pragma unroll
            for (int reg = 0; reg < 4; ++reg) {
                int tok = m * 16 + g * 4 + reg;
                dst[(size_t)tok * 64 + nt * 16 + l15] = acc[m][nt][reg] + bo;
            }
        }
    }
}

// ---------------- K3: per-(t,c) spatial mean (NHWC input) -------------------
__global__ __launch_bounds__(256) void k3_mean(
        const float* __restrict__ xs, float* __restrict__ mean) {
    __shared__ f32x4 red[256];
    int t = blockIdx.x;
    int c4 = threadIdx.x & 15, q = threadIdx.x >> 4;
    const float* base = xs + (size_t)t * PX * 64 + c4 * 4;
    f32x4 s = (f32x4)0.f;
    for (int px = q; px < PX; px += 16)
        s += *(const f32x4*)&base[(size_t)px * 64];
    red[threadIdx.x] = s;
    __syncthreads();
    for (int st = 8; st > 0; st >>= 1) {
        if (q < st) red[q * 16 + c4] += red[(q + st) * 16 + c4];
        __syncthreads();
    }
    if (q == 0) {
        f32x4 v = red[c4] * (1.f / 4096.f);
        *(f32x4*)&mean[t * 64 + c4 * 4] = v;
    }
}

// ---------------- K4: decay/forcing tables + flux scan ----------------------
__global__ __launch_bounds__(256) void k4_ops(
        const float* __restrict__ dt, const float* __restrict__ lam_re,
        const float* __restrict__ lam_im, const float* __restrict__ alpha,
        const float* __restrict__ wre, const float* __restrict__ wim,
        const float* __restrict__ mean, float* __restrict__ tabs,
        float* __restrict__ outflux) {
    int tid = threadIdx.x;
    for (int idx = tid; idx < 1024; idx += 256) {
        int t = idx >> 5, d = idx & 31;
        float x = lam_re[d];
        float sp = (x > 0.f) ? x + log1pf(expf(-x)) : log1pf(expf(x));
        float lr = -sp, li = lam_im[d];
        float dtv = dt[t];
        float er = expf(lr * dtv);
        float dr = er * cosf(li * dtv);
        float di = er * sinf(li * dtv);
        float den = lr * lr + li * li;
        float fr = ((dr - 1.f) * lr + di * li) / den;
        float fi = (di * lr - (dr - 1.f) * li) / den;
        tabs[idx] = dr; tabs[1024 + idx] = di;
        tabs[2048 + idx] = fr; tabs[3072 + idx] = fi;
    }
    if (tid < 32) {
        int d = tid;
        float a = 1.f / (1.f + expf(-alpha[d]));
        float yr = 0.f, yi = 0.f;
        for (int t = 0; t < 32; ++t) {
            float xr = 0.f, xi = 0.f;
            for (int k = 0; k < 32; ++k) {
                float mr = mean[t * 64 + k], mi = mean[t * 64 + 32 + k];
                float wr = wre[k * 32 + d], wi = wim[k * 32 + d];
                xr += mr * wr - mi * wi;
                xi += mr * wi + mi * wr;
            }
            yr = a * yr + xr; yi = a * yi + xi;
        }
        outflux[d] = yr; outflux[32 + d] = yi;
    }
}

// ---------------- K5: enc matmul + time scan + noise + dec matmul -----------
__global__ __launch_bounds__(256) void k5_seq(
        const float* __restrict__ xs,
        const float* __restrict__ enc_re, const float* __restrict__ enc_im,
        const float* __restrict__ dec_re, const float* __restrict__ dec_im,
        const float* __restrict__ tabs, const float* __restrict__ dt,
        const float* __restrict__ eps_re, const float* __restrict__ eps_im,
        float* __restrict__ xo) {
    __shared__ float xsl[8 * 64];
    __shared__ float uol[8 * 64];
    int tid = threadIdx.x;
    int lpx = tid >> 5, d = tid & 31;
    int pxbase = blockIdx.x * 8;
    float eR[32], eI[32], dR[32], dI[32];
    #pragma unroll
    for (int k = 0; k < 32; ++k) {
        eR[k] = enc_re[k * 32 + d]; eI[k] = enc_im[k * 32 + d];
        dR[k] = dec_re[k * 32 + d]; dI[k] = dec_im[k * 32 + d];
    }
    float Yr = 0.f, Yi = 0.f;
    for (int t = 0; t < TT; ++t) {
        for (int idx = tid; idx < 512; idx += 256) {
            int p = idx >> 6, c = idx & 63;
            xsl[p * 64 + c] = xs[((size_t)t * PX + pxbase + p) * 64 + c];
        }
        __syncthreads();
        float ur = 0.f, ui = 0.f;
        #pragma unroll
        for (int k = 0; k < 32; ++k) {
            float xr = xsl[lpx * 64 + k], xi = xsl[lpx * 64 + 32 + k];
            ur += xr * eR[k] - xi * eI[k];
            ui += xr * eI[k] + xi * eR[k];
        }
        float drr = tabs[t * 32 + d],        dii = tabs[1024 + t * 32 + d];
        float fr  = tabs[2048 + t * 32 + d], fi  = tabs[3072 + t * 32 + d];
        float usr = ur * fr - ui * fi;
        float usi = ur * fi + ui * fr;
        float nYr = drr * Yr - dii * Yi + usr;
        float nYi = drr * Yi + dii * Yr + usi;
        Yr = nYr; Yi = nYi;
        float s = 0.01f * sqrtf(dt[t]);
        size_t ei = ((size_t)t * PX + pxbase + lpx) * 32 + d;
        float epr = eps_re[ei], epi = eps_im[ei];
        float nr = Yr * epr - Yi * epi;
        float ni = Yr * epi + Yi * epr;
        uol[lpx * 64 + d]      = Yr + s * nr;
        uol[lpx * 64 + 32 + d] = Yi + s * ni;
        __syncthreads();
        float xr2 = 0.f, xi2 = 0.f;
        #pragma unroll
        for (int k = 0; k < 32; ++k) {
            float ar = uol[lpx * 64 + k], ai = uol[lpx * 64 + 32 + k];
            xr2 += ar * dR[k] - ai * dI[k];
            xi2 += ar * dI[k] + ai * dR[k];
        }
        size_t ob = ((size_t)t * PX + pxbase + lpx) * 64;
        xo[ob + d]      = xr2;
        xo[ob + 32 + d] = xi2;
        __syncthreads();
    }
}

// ---------------- K6: LN2 + gated MoE MLP (bf16 MFMA) + residual write ------
// R6 dataflow; LDS cut 75.8->49.8 KB (3 blk/CU): fA/H union, per-matrix
// weight staging, delta accumulated into fld in place.
__global__ __launch_bounds__(256, 3) void k6_moe(
        const float* __restrict__ xo,
        const float* __restrict__ g2, const float* __restrict__ b2ln,
        const float* __restrict__ wg,
        const unsigned short* __restrict__ w1t, const float* __restrict__ b1,
        const unsigned short* __restrict__ w2t, const float* __restrict__ b2m,
        const float* __restrict__ xre, const float* __restrict__ xim,
        float* __restrict__ out) {
    __shared__ __align__(16) float fld[64 * 65];           // 16.6 KB f32 f (then f+delta)
    __shared__ __align__(16) unsigned short fAH[64 * 128]; // 16 KB: fA (first 8KB), then H
    __shared__ __align__(16) unsigned short wst[8192];     // 16 KB: one weight matrix
    __shared__ float gate[64 * 4];
    __shared__ float stat[128];

    int tid = threadIdx.x;
    int lane = tid & 63;
    int wv = tid >> 6;
    int t = blockIdx.x >> 6;
    int px0 = (blockIdx.x & 63) * 64;

    {
        const float4* src = (const float4*)(xo + ((size_t)t * PX + px0) * 64);
        #pragma unroll
        for (int i = 0; i < 4; ++i) {
            int idx = i * 256 + tid;
            int tok = idx >> 4, c4 = idx & 15;
            float4 v = src[idx];
            float* dst = &fld[tok * 65 + c4 * 4];
            dst[0] = v.x; dst[1] = v.y; dst[2] = v.z; dst[3] = v.w;
        }
    }
    __syncthreads();
    {
        int tok = tid >> 2, q = tid & 3;
        float s = 0.f, ss = 0.f;
        #pragma unroll
        for (int i = 0; i < 16; ++i) {
            float v = fld[tok * 65 + q * 16 + i];
            s += v; ss += v * v;
        }
        s += __shfl_xor(s, 1); ss += __shfl_xor(ss, 1);
        s += __shfl_xor(s, 2); ss += __shfl_xor(ss, 2);
        if (q == 0) {
            float m = s * (1.f / 64.f);
            float var = ss * (1.f / 64.f) - m * m;
            stat[tok] = m; stat[64 + tok] = rsqrtf(var + 1e-5f);
        }
    }
    __syncthreads();
    #pragma unroll
    for (int r = 0; r < 16; ++r) {
        int idx = r * 256 + tid;
        int tok = idx >> 6, c = idx & 63;
        float v = (fld[tok * 65 + c] - stat[tok]) * stat[64 + tok] * g2[c] + b2ln[c];
        fld[tok * 65 + c] = v;
        fAH[tok * 64 + (c & 7) + 8 * ((c >> 3) ^ (tok & 7))] = f2b(v);
    }
    __syncthreads();
    {
        int tok = tid >> 2, e = tid & 3;
        float acc = 0.f;
        #pragma unroll 8
        for (int c = 0; c < 64; ++c) acc += fld[tok * 65 + c] * wg[c * 4 + e];
        gate[tok * 4 + e] = acc;
    }
    __syncthreads();
    if (tid < 64) {
        float l0 = gate[tid*4], l1 = gate[tid*4+1], l2 = gate[tid*4+2], l3 = gate[tid*4+3];
        float mx = fmaxf(fmaxf(l0, l1), fmaxf(l2, l3));
        float e0 = expf(l0-mx), e1 = expf(l1-mx), e2 = expf(l2-mx), e3 = expf(l3-mx);
        float inv = 1.f / (e0 + e1 + e2 + e3);
        gate[tid*4] = e0*inv; gate[tid*4+1] = e1*inv; gate[tid*4+2] = e2*inv; gate[tid*4+3] = e3*inv;
    }

    int l15 = lane & 15, g = lane >> 4;
    int row0 = wv * 16 + l15;
    int rowb = wv * 16 + g * 4;

    // A fragments into registers; fAH free for H after the e=0 barrier
    short8v a1[2];
    #pragma unroll
    for (int st = 0; st < 2; ++st) {
        int chunk = (st * 4 + g) ^ (row0 & 7);
        a1[st] = *(const short8v*)&fAH[row0 * 64 + chunk * 8];
    }

    f32x4 dacc[4];
    #pragma unroll
    for (int i = 0; i < 4; ++i) dacc[i] = (f32x4)0.f;

    for (int e = 0; e < 4; ++e) {
        __syncthreads();   // (A) a1 reads done (e=0) / prev GEMM2 wst+H reads done
        {   // stage w1e (16 KB)
            const short8v* gp = (const short8v*)(w1t + (size_t)e * 8192);
            #pragma unroll
            for (int i = 0; i < 4; ++i)
                *(short8v*)&wst[(i * 256 + tid) * 8] = gp[i * 256 + tid];
        }
        __syncthreads();   // (B) w1e ready
        // GEMM1: H = gelu(f @ w1e + b1e)
        f32x4 h[8];
        #pragma unroll
        for (int i = 0; i < 8; ++i) h[i] = (f32x4)0.f;
        #pragma unroll
        for (int st = 0; st < 2; ++st) {
            #pragma unroll
            for (int nt = 0; nt < 8; ++nt) {
                int n = nt * 16 + l15;
                int chunk = (st * 4 + g) ^ (n & 7);
                short8v b = *(const short8v*)&wst[n * 64 + chunk * 8];
                h[nt] = __builtin_amdgcn_mfma_f32_16x16x32_bf16(a1[st], b, h[nt], 0, 0, 0);
            }
        }
        #pragma unroll
        for (int nt = 0; nt < 8; ++nt) {
            int f = nt * 16 + l15;
            float bb = b1[e * 128 + f];
            #pragma unroll
            for (int r = 0; r < 4; ++r) {
                int row = rowb + r;
                float v = gelu_fast(h[nt][r] + bb);
                fAH[row * 128 + (f & 7) + 8 * ((f >> 3) ^ (row & 7))] = f2b(v);
            }
        }
        __syncthreads();   // (C) GEMM1 wst reads done + H complete
        {   // stage w2e (16 KB)
            const short8v* gp = (const short8v*)(w2t + (size_t)e * 8192);
            #pragma unroll
            for (int i = 0; i < 4; ++i)
                *(short8v*)&wst[(i * 256 + tid) * 8] = gp[i * 256 + tid];
        }
        __syncthreads();   // (D) w2e ready
        // GEMM2: eo = H @ w2e ; dacc += gate_e * (eo + b2e)
        f32x4 eo[4];
        #pragma unroll
        for (int i = 0; i < 4; ++i) eo[i] = (f32x4)0.f;
        #pragma unroll
        for (int st = 0; st < 4; ++st) {
            int chunkA = (st * 4 + g) ^ (row0 & 7);
            short8v a2 = *(const short8v*)&fAH[row0 * 128 + chunkA * 8];
            #pragma unroll
            for (int nt = 0; nt < 4; ++nt) {
                int n = nt * 16 + l15;
                int chunk = (st * 4 + g) ^ (n & 7);
                short8v b = *(const short8v*)&wst[n * 128 + chunk * 8];
                eo[nt] = __builtin_amdgcn_mfma_f32_16x16x32_bf16(a2, b, eo[nt], 0, 0, 0);
            }
        }
        #pragma unroll
        for (int nt = 0; nt < 4; ++nt) {
            int c = nt * 16 + l15;
            float bb = b2m[e * 64 + c];
            #pragma unroll
            for (int r = 0; r < 4; ++r) {
                float gt = gate[(rowb + r) * 4 + e];
                dacc[nt][r] += gt * (eo[nt][r] + bb);
            }
        }
    }
    __syncthreads();   // all H/wst reads done; fld stable since normalize
    // delta += into fld in place (each (row,c) owned by exactly one thread)
    #pragma unroll
    for (int nt = 0; nt < 4; ++nt) {
        int c = nt * 16 + l15;
        #pragma unroll
        for (int r = 0; r < 4; ++r)
            fld[(rowb + r) * 65 + c] += dacc[nt][r];
    }
    __syncthreads();
    #pragma unroll
    for (int r = 0; r < 16; ++r) {
        int idx = r * 256 + tid;
        int c = idx >> 6, tok = idx & 63;
        float val = fld[tok * 65 + c];
        size_t xi_ = ((size_t)t * 32 + (c & 31)) * PX + px0 + tok;
        float xv = (c < 32) ? xre[xi_] : xim[xi_];
        out[(size_t)(c < 32 ? 0 : 4194304) + xi_] = val + xv;
    }
}

extern "C" void kernel_launch(void* const* d_in, const int* in_sizes, int n_in,
                              void* d_out, int out_size, void* d_ws, size_t ws_size,
                              hipStream_t stream) {
    const float* xre   = (const float*)d_in[0];
    const float* xim   = (const float*)d_in[1];
    const float* dt    = (const float*)d_in[2];
    const float* epsre = (const float*)d_in[3];
    const float* epsim = (const float*)d_in[4];
    const float* ln1g  = (const float*)d_in[5];
    const float* ln1b  = (const float*)d_in[6];
    const float* ln2g  = (const float*)d_in[7];
    const float* ln2b  = (const float*)d_in[8];
    const float* convw = (const float*)d_in[9];
    const float* convb = (const float*)d_in[10];
    const float* encre = (const float*)d_in[11];
    const float* encim = (const float*)d_in[12];
    const float* decre = (const float*)d_in[13];
    const float* decim = (const float*)d_in[14];
    const float* lamre = (const float*)d_in[15];
    const float* lamim = (const float*)d_in[16];
    const float* alpha = (const float*)d_in[17];
    const float* fwre  = (const float*)d_in[18];
    const float* fwim  = (const float*)d_in[19];
    const float* wg    = (const float*)d_in[20];
    const float* w1    = (const float*)d_in[21];
    const float* b1    = (const float*)d_in[22];
    const float* w2    = (const float*)d_in[23];
    const float* b2    = (const float*)d_in[24];
    float* out = (float*)d_out;

    float* ws = (float*)d_ws;
    unsigned short* xpad = (unsigned short*)ws;   // region A: xpad bf16 then xo f32
    float* xo   = ws;
    float* xs   = ws + 8388608;         // NHWC f32 conv output
    float* mean = ws + 16777216;
    float* tabs = ws + 16779264;
    unsigned short* w1t = (unsigned short*)(ws + 16783360);
    unsigned short* w2t = w1t + 32768;
    unsigned short* w9t = w2t + 32768;

    k0_prep<<<400, 256, 0, stream>>>(w1, w2, convw, w1t, w2t, w9t);
    kz_halo<<<33, 256, 0, stream>>>(xpad);
    k1_ln1<<<512, 256, 0, stream>>>(xre, xim, ln1g, ln1b, xpad);
    k2_conv<<<512, 256, 0, stream>>>(xpad, w9t, convb, xs);
    k3_mean<<<32, 256, 0, stream>>>(xs, mean);
    k4_ops<<<1, 256, 0, stream>>>(dt, lamre, lamim, alpha, fwre, fwim, mean,
                                  tabs, out + 8388608);
    k5_seq<<<512, 256, 0, stream>>>(xs, encre, encim, decre, decim, tabs, dt,
                                    epsre, epsim, xo);
    k6_moe<<<2048, 256, 0, stream>>>(xo, ln2g, ln2b, wg, w1t, b1, w2t, b2,
                                     xre, xim, out);
}

// Round 8
// 289.458 us; speedup vs baseline: 3.7447x; 1.0866x over previous
//
#include <hip/hip_runtime.h>
#include <math.h>

#define PX 4096   // 64*64
#define TT 32
#define DD 32
#define CC 64     // 2*D
#define PW 66     // padded width
#define PPX 4356  // 66*66

typedef __attribute__((ext_vector_type(8))) short short8v;
typedef __attribute__((ext_vector_type(4))) float f32x4;

__device__ __forceinline__ float gelu_fast(float x) {
    // gelu_tanh(x) == x * sigmoid(2z), z = 0.7978845608*(x + 0.044715 x^3)
    float u = x * x;
    float a = x * (1.5957691216057308f + 0.07135481627f * u);
    return x / (1.0f + __expf(-a));
}

__device__ __forceinline__ unsigned short f2b(float x) {
    union { float f; unsigned u; } v; v.f = x;
    unsigned r = v.u + 0x7FFF + ((v.u >> 16) & 1);
    return (unsigned short)(r >> 16);
}

// ---------------- K1: LN1 (64ch) fused -> padded bf16 NHWC ------------------
__global__ __launch_bounds__(256) void k1_ln1(
        const float* __restrict__ xre, const float* __restrict__ xim,
        const float* __restrict__ g, const float* __restrict__ b,
        unsigned short* __restrict__ xpad) {
    int gid = blockIdx.x * 256 + threadIdx.x;   // t*4096 + px
    int t = gid >> 12, px = gid & 4095;
    int row = px >> 6, col = px & 63;
    const float* pr = xre + (size_t)t * DD * PX + px;
    const float* pi = xim + (size_t)t * DD * PX + px;
    float s = 0.f, ss = 0.f;
    #pragma unroll
    for (int d = 0; d < DD; ++d) {
        float vr = pr[d * PX], vi = pi[d * PX];
        s += vr + vi; ss += vr * vr + vi * vi;
    }
    float m = s * (1.f / 64.f);
    float var = ss * (1.f / 64.f) - m * m;
    float rs = rsqrtf(var + 1e-5f);
    unsigned short* o = xpad + ((size_t)t * PPX + (row + 1) * PW + (col + 1)) * 64;
    #pragma unroll
    for (int j = 0; j < 8; ++j) {
        short8v v8;
        #pragma unroll
        for (int dd = 0; dd < 8; ++dd) {
            int ch = j * 8 + dd;
            float v = (ch < 32) ? (pr[ch * PX] - m) * rs * g[ch] + b[ch]
                                : (pi[(ch - 32) * PX] - m) * rs * g[ch] + b[ch];
            v8[dd] = (short)f2b(v);
        }
        *(short8v*)&o[j * 8] = v8;
    }
}

// ---------------- KZ: zero the halo of xpad ---------------------------------
__global__ __launch_bounds__(256) void kz_halo(unsigned short* __restrict__ xpad) {
    int gid = blockIdx.x * 256 + threadIdx.x;
    if (gid >= 32 * 260) return;
    int im = gid / 260, h = gid % 260;
    int row, col;
    if (h < 66)       { row = 0;  col = h; }
    else if (h < 132) { row = 65; col = h - 66; }
    else { int hh = h - 132; row = 1 + (hh >> 1); col = (hh & 1) * 65; }
    unsigned short* p = xpad + ((size_t)im * PPX + row * PW + col) * 64;
    short8v z = (short8v)0;
    #pragma unroll
    for (int j = 0; j < 8; ++j) *(short8v*)&p[j * 8] = z;
}

// ---------------- K0: prep — bf16/transpose/swizzle all weight matrices -----
// w1t[e][f][c'], c' = (c&7)+8*((c>>3)^(f&7)), val = w1[e][c][f]
// w2t[e][n][f'], f' = (f&7)+8*((f>>3)^(n&7)), val = w2[e][f][n]
// w9t[tap][o][i'], val = convw[o][i][tap]
// benct[n][k'] 64x64: complex enc as real block matrix [[Er,Ei],[-Ei,Er]]
// bdect[n][k'] 64x64: same for dec
__global__ __launch_bounds__(256) void k0_prep(
        const float* __restrict__ w1, const float* __restrict__ w2,
        const float* __restrict__ convw,
        const float* __restrict__ encre, const float* __restrict__ encim,
        const float* __restrict__ decre, const float* __restrict__ decim,
        unsigned short* __restrict__ w1t, unsigned short* __restrict__ w2t,
        unsigned short* __restrict__ w9t,
        unsigned short* __restrict__ benct, unsigned short* __restrict__ bdect) {
    int gid = blockIdx.x * 256 + threadIdx.x;
    if (gid < 32768) {
        int idx = gid;
        int e = idx >> 13, r = idx & 8191;
        int f = r >> 6, p = r & 63;
        int c = (p & 7) + 8 * ((p >> 3) ^ (f & 7));
        w1t[idx] = f2b(w1[((size_t)e * 64 + c) * 128 + f]);
    } else if (gid < 65536) {
        int idx = gid - 32768;
        int e = idx >> 13, r = idx & 8191;
        int n = r >> 7, p = r & 127;
        int f = (p & 7) + 8 * ((p >> 3) ^ (n & 7));
        w2t[idx] = f2b(w2[((size_t)e * 128 + f) * 64 + n]);
    } else if (gid < 102400) {
        int idx = gid - 65536;
        int tap = idx >> 12, rem = idx & 4095;
        int n = rem >> 6, p = rem & 63;
        int k = (p & 7) + 8 * ((p >> 3) ^ (n & 7));
        w9t[idx] = f2b(convw[((size_t)n * 64 + k) * 9 + tap]);
    } else if (gid < 110592) {
        int idx = gid - 102400;
        const float* Rr = (idx < 4096) ? encre : decre;
        const float* Ri = (idx < 4096) ? encim : decim;
        unsigned short* dst = (idx < 4096) ? benct : bdect;
        idx &= 4095;
        int n = idx >> 6, p = idx & 63;
        int k = (p & 7) + 8 * ((p >> 3) ^ (n & 7));
        float v;
        if (n < 32) v = (k < 32) ? Rr[k * 32 + n] : -Ri[(k - 32) * 32 + n];
        else        v = (k < 32) ? Ri[k * 32 + (n - 32)] : Rr[(k - 32) * 32 + (n - 32)];
        dst[idx] = f2b(v);
    }
}

// ---------------- K2: 3x3 conv 64->64 as 9-tap implicit GEMM (bf16 MFMA) ----
__global__ __launch_bounds__(256, 2) void k2_conv(
        const unsigned short* __restrict__ xpad,
        const unsigned short* __restrict__ w9t,
        const float* __restrict__ bias, float* __restrict__ xs) {
    __shared__ __align__(16) unsigned short wst[36864];   // 9 taps x 64oc x 64ic swz
    int tid = threadIdx.x;
    int bid = blockIdx.x;
    int lb = (bid & 7) * 64 + (bid >> 3);   // bijective (512 % 8 == 0)
    int t = lb >> 4, rg = lb & 15;
    int lane = tid & 63, wv = tid >> 6;
    int l15 = lane & 15, g = lane >> 4;
    #pragma unroll
    for (int i = 0; i < 18; ++i) {
        int idx = i * 256 + tid;
        *(short8v*)&wst[idx * 8] = *(const short8v*)&w9t[idx * 8];
    }
    __syncthreads();
    int r = rg * 4 + wv;
    const unsigned short* xb = xpad + (size_t)t * PPX * 64;
    f32x4 acc[4][4];
    #pragma unroll
    for (int m = 0; m < 4; ++m)
        #pragma unroll
        for (int nt = 0; nt < 4; ++nt) acc[m][nt] = (f32x4)0.f;

    #pragma unroll
    for (int kh = 0; kh < 3; ++kh) {
        #pragma unroll
        for (int kw = 0; kw < 3; ++kw) {
            int tap = kh * 3 + kw;
            #pragma unroll
            for (int kc = 0; kc < 2; ++kc) {
                short8v a[4];
                #pragma unroll
                for (int m = 0; m < 4; ++m) {
                    int pcol = m * 16 + l15 + kw;
                    a[m] = *(const short8v*)&xb[((size_t)(r + kh) * PW + pcol) * 64 + kc * 32 + g * 8];
                }
                #pragma unroll
                for (int nt = 0; nt < 4; ++nt) {
                    int n = nt * 16 + l15;
                    short8v bf = *(const short8v*)&wst[tap * 4096 + n * 64 + ((kc * 4 + g) ^ (n & 7)) * 8];
                    #pragma unroll
                    for (int m = 0; m < 4; ++m)
                        acc[m][nt] = __builtin_amdgcn_mfma_f32_16x16x32_bf16(a[m], bf, acc[m][nt], 0, 0, 0);
                }
            }
        }
    }
    float* dst = xs + ((size_t)t * PX + r * 64) * 64;
    #pragma unroll
    for (int nt = 0; nt < 4; ++nt) {
        float bo = bias[nt * 16 + l15];
        #pragma unroll
        for (int m = 0; m < 4; ++m) {
            #pragma unroll
            for (int reg = 0; reg < 4; ++reg) {
                int tok = m * 16 + g * 4 + reg;
                dst[(size_t)tok * 64 + nt * 16 + l15] = acc[m][nt][reg] + bo;
            }
        }
    }
}

// ---------------- K3: per-(t,c) spatial mean (NHWC input) -------------------
__global__ __launch_bounds__(256) void k3_mean(
        const float* __restrict__ xs, float* __restrict__ mean) {
    __shared__ f32x4 red[256];
    int t = blockIdx.x;
    int c4 = threadIdx.x & 15, q = threadIdx.x >> 4;
    const float* base = xs + (size_t)t * PX * 64 + c4 * 4;
    f32x4 s = (f32x4)0.f;
    for (int px = q; px < PX; px += 16)
        s += *(const f32x4*)&base[(size_t)px * 64];
    red[threadIdx.x] = s;
    __syncthreads();
    for (int st = 8; st > 0; st >>= 1) {
        if (q < st) red[q * 16 + c4] += red[(q + st) * 16 + c4];
        __syncthreads();
    }
    if (q == 0) {
        f32x4 v = red[c4] * (1.f / 4096.f);
        *(f32x4*)&mean[t * 64 + c4 * 4] = v;
    }
}

// ---------------- K4: decay/forcing tables + flux scan ----------------------
__global__ __launch_bounds__(256) void k4_ops(
        const float* __restrict__ dt, const float* __restrict__ lam_re,
        const float* __restrict__ lam_im, const float* __restrict__ alpha,
        const float* __restrict__ wre, const float* __restrict__ wim,
        const float* __restrict__ mean, float* __restrict__ tabs,
        float* __restrict__ outflux) {
    int tid = threadIdx.x;
    for (int idx = tid; idx < 1024; idx += 256) {
        int t = idx >> 5, d = idx & 31;
        float x = lam_re[d];
        float sp = (x > 0.f) ? x + log1pf(expf(-x)) : log1pf(expf(x));
        float lr = -sp, li = lam_im[d];
        float dtv = dt[t];
        float er = expf(lr * dtv);
        float dr = er * cosf(li * dtv);
        float di = er * sinf(li * dtv);
        float den = lr * lr + li * li;
        float fr = ((dr - 1.f) * lr + di * li) / den;
        float fi = (di * lr - (dr - 1.f) * li) / den;
        tabs[idx] = dr; tabs[1024 + idx] = di;
        tabs[2048 + idx] = fr; tabs[3072 + idx] = fi;
    }
    if (tid < 32) {
        int d = tid;
        float a = 1.f / (1.f + expf(-alpha[d]));
        float yr = 0.f, yi = 0.f;
        for (int t = 0; t < 32; ++t) {
            float xr = 0.f, xi = 0.f;
            for (int k = 0; k < 32; ++k) {
                float mr = mean[t * 64 + k], mi = mean[t * 64 + 32 + k];
                float wr = wre[k * 32 + d], wi = wim[k * 32 + d];
                xr += mr * wr - mi * wi;
                xi += mr * wi + mi * wr;
            }
            yr = a * yr + xr; yi = a * yi + xi;
        }
        outflux[d] = yr; outflux[32 + d] = yi;
    }
}

// ---------------- K5a/K5c: token GEMM (64 tok/block) vs 64x64 bf16 B --------
// A rows = 64 f32 channels; B pre-swizzled in global. FORCING: multiply the
// complex (Ur,Ui) output pairs by op_forcing[t,d] in-register (epilogue).
// Safe in-place (O may == A): per-block token ranges are disjoint and the
// A-tile is fully staged to LDS (barrier) before any epilogue write.
template<bool FORCING>
__global__ __launch_bounds__(256) void k5_gemm(
        const float* A, const unsigned short* __restrict__ Bt,
        const float* __restrict__ tabs, float* O) {
    __shared__ __align__(16) unsigned short fA[64 * 64];
    __shared__ __align__(16) unsigned short bst[64 * 64];
    int tid = threadIdx.x;
    int lane = tid & 63, wv = tid >> 6;
    size_t tok0 = (size_t)blockIdx.x * 64;
    #pragma unroll
    for (int i = 0; i < 2; ++i)
        *(short8v*)&bst[(i * 256 + tid) * 8] = *(const short8v*)&Bt[(i * 256 + tid) * 8];
    #pragma unroll
    for (int r = 0; r < 16; ++r) {
        int idx = r * 256 + tid;
        int tok = idx >> 6, c = idx & 63;
        fA[tok * 64 + (c & 7) + 8 * ((c >> 3) ^ (tok & 7))] = f2b(A[(tok0 + tok) * 64 + c]);
    }
    __syncthreads();
    int l15 = lane & 15, g = lane >> 4;
    int row0 = wv * 16 + l15;
    int rowb = wv * 16 + g * 4;
    short8v a1[2];
    #pragma unroll
    for (int st = 0; st < 2; ++st)
        a1[st] = *(const short8v*)&fA[row0 * 64 + (((st * 4 + g) ^ (row0 & 7))) * 8];
    f32x4 eo[4];
    #pragma unroll
    for (int i = 0; i < 4; ++i) eo[i] = (f32x4)0.f;
    #pragma unroll
    for (int st = 0; st < 2; ++st) {
        #pragma unroll
        for (int nt = 0; nt < 4; ++nt) {
            int n = nt * 16 + l15;
            short8v b = *(const short8v*)&bst[n * 64 + (((st * 4 + g) ^ (n & 7))) * 8];
            eo[nt] = __builtin_amdgcn_mfma_f32_16x16x32_bf16(a1[st], b, eo[nt], 0, 0, 0);
        }
    }
    if (FORCING) {
        int t = (int)(tok0 >> 12);
        #pragma unroll
        for (int p = 0; p < 2; ++p) {
            int d = p * 16 + l15;
            float fr = tabs[2048 + t * 32 + d], fi = tabs[3072 + t * 32 + d];
            #pragma unroll
            for (int r = 0; r < 4; ++r) {
                float ur = eo[p][r], ui = eo[p + 2][r];
                eo[p][r]     = ur * fr - ui * fi;
                eo[p + 2][r] = ur * fi + ui * fr;
            }
        }
    }
    #pragma unroll
    for (int nt = 0; nt < 4; ++nt) {
        int n = nt * 16 + l15;
        #pragma unroll
        for (int r = 0; r < 4; ++r)
            O[(tok0 + rowb + r) * 64 + n] = eo[nt][r];
    }
}

// ---------------- K5b: time scan + noise, pure streaming (in-place) ---------
__global__ __launch_bounds__(256) void k5b_scan(
        float* U, const float* __restrict__ tabs, const float* __restrict__ dt,
        const float* __restrict__ eps_re, const float* __restrict__ eps_im) {
    int gid = blockIdx.x * 256 + threadIdx.x;   // px*32 + d
    int px = gid >> 5, d = gid & 31;
    float Yr = 0.f, Yi = 0.f;
    for (int t = 0; t < TT; ++t) {
        size_t tok = (size_t)t * PX + px;
        float usr = U[tok * 64 + d], usi = U[tok * 64 + 32 + d];
        float dr = tabs[t * 32 + d], di = tabs[1024 + t * 32 + d];
        float nYr = dr * Yr - di * Yi + usr;
        float nYi = dr * Yi + di * Yr + usi;
        Yr = nYr; Yi = nYi;
        float s = 0.01f * sqrtf(dt[t]);
        size_t ei = tok * 32 + d;
        float epr = eps_re[ei], epi = eps_im[ei];
        U[tok * 64 + d]      = Yr + s * (Yr * epr - Yi * epi);
        U[tok * 64 + 32 + d] = Yi + s * (Yr * epi + Yi * epr);
    }
}

// ---------------- K6: LN2 + gated MoE MLP (bf16 MFMA) + residual write ------
__global__ __launch_bounds__(256, 3) void k6_moe(
        const float* __restrict__ xo,
        const float* __restrict__ g2, const float* __restrict__ b2ln,
        const float* __restrict__ wg,
        const unsigned short* __restrict__ w1t, const float* __restrict__ b1,
        const unsigned short* __restrict__ w2t, const float* __restrict__ b2m,
        const float* __restrict__ xre, const float* __restrict__ xim,
        float* __restrict__ out) {
    __shared__ __align__(16) float fld[64 * 65];           // 16.6 KB f32 f (then f+delta)
    __shared__ __align__(16) unsigned short fAH[64 * 128]; // 16 KB: fA (first 8KB), then H
    __shared__ __align__(16) unsigned short wst[8192];     // 16 KB: one weight matrix
    __shared__ float gate[64 * 4];
    __shared__ float stat[128];

    int tid = threadIdx.x;
    int lane = tid & 63;
    int wv = tid >> 6;
    int t = blockIdx.x >> 6;
    int px0 = (blockIdx.x & 63) * 64;

    {
        const float4* src = (const float4*)(xo + ((size_t)t * PX + px0) * 64);
        #pragma unroll
        for (int i = 0; i < 4; ++i) {
            int idx = i * 256 + tid;
            int tok = idx >> 4, c4 = idx & 15;
            float4 v = src[idx];
            float* dst = &fld[tok * 65 + c4 * 4];
            dst[0] = v.x; dst[1] = v.y; dst[2] = v.z; dst[3] = v.w;
        }
    }
    __syncthreads();
    {
        int tok = tid >> 2, q = tid & 3;
        float s = 0.f, ss = 0.f;
        #pragma unroll
        for (int i = 0; i < 16; ++i) {
            float v = fld[tok * 65 + q * 16 + i];
            s += v; ss += v * v;
        }
        s += __shfl_xor(s, 1); ss += __shfl_xor(ss, 1);
        s += __shfl_xor(s, 2); ss += __shfl_xor(ss, 2);
        if (q == 0) {
            float m = s * (1.f / 64.f);
            float var = ss * (1.f / 64.f) - m * m;
            stat[tok] = m; stat[64 + tok] = rsqrtf(var + 1e-5f);
        }
    }
    __syncthreads();
    #pragma unroll
    for (int r = 0; r < 16; ++r) {
        int idx = r * 256 + tid;
        int tok = idx >> 6, c = idx & 63;
        float v = (fld[tok * 65 + c] - stat[tok]) * stat[64 + tok] * g2[c] + b2ln[c];
        fld[tok * 65 + c] = v;
        fAH[tok * 64 + (c & 7) + 8 * ((c >> 3) ^ (tok & 7))] = f2b(v);
    }
    __syncthreads();
    {
        int tok = tid >> 2, e = tid & 3;
        float acc = 0.f;
        #pragma unroll 8
        for (int c = 0; c < 64; ++c) acc += fld[tok * 65 + c] * wg[c * 4 + e];
        gate[tok * 4 + e] = acc;
    }
    __syncthreads();
    if (tid < 64) {
        float l0 = gate[tid*4], l1 = gate[tid*4+1], l2 = gate[tid*4+2], l3 = gate[tid*4+3];
        float mx = fmaxf(fmaxf(l0, l1), fmaxf(l2, l3));
        float e0 = expf(l0-mx), e1 = expf(l1-mx), e2 = expf(l2-mx), e3 = expf(l3-mx);
        float inv = 1.f / (e0 + e1 + e2 + e3);
        gate[tid*4] = e0*inv; gate[tid*4+1] = e1*inv; gate[tid*4+2] = e2*inv; gate[tid*4+3] = e3*inv;
    }

    int l15 = lane & 15, g = lane >> 4;
    int row0 = wv * 16 + l15;
    int rowb = wv * 16 + g * 4;

    short8v a1[2];
    #pragma unroll
    for (int st = 0; st < 2; ++st) {
        int chunk = (st * 4 + g) ^ (row0 & 7);
        a1[st] = *(const short8v*)&fAH[row0 * 64 + chunk * 8];
    }

    f32x4 dacc[4];
    #pragma unroll
    for (int i = 0; i < 4; ++i) dacc[i] = (f32x4)0.f;

    for (int e = 0; e < 4; ++e) {
        __syncthreads();   // (A) a1 reads done (e=0) / prev GEMM2 wst+H reads done
        {
            const short8v* gp = (const short8v*)(w1t + (size_t)e * 8192);
            #pragma unroll
            for (int i = 0; i < 4; ++i)
                *(short8v*)&wst[(i * 256 + tid) * 8] = gp[i * 256 + tid];
        }
        __syncthreads();   // (B) w1e ready
        f32x4 h[8];
        #pragma unroll
        for (int i = 0; i < 8; ++i) h[i] = (f32x4)0.f;
        #pragma unroll
        for (int st = 0; st < 2; ++st) {
            #pragma unroll
            for (int nt = 0; nt < 8; ++nt) {
                int n = nt * 16 + l15;
                int chunk = (st * 4 + g) ^ (n & 7);
                short8v b = *(const short8v*)&wst[n * 64 + chunk * 8];
                h[nt] = __builtin_amdgcn_mfma_f32_16x16x32_bf16(a1[st], b, h[nt], 0, 0, 0);
            }
        }
        #pragma unroll
        for (int nt = 0; nt < 8; ++nt) {
            int f = nt * 16 + l15;
            float bb = b1[e * 128 + f];
            #pragma unroll
            for (int r = 0; r < 4; ++r) {
                int row = rowb + r;
                float v = gelu_fast(h[nt][r] + bb);
                fAH[row * 128 + (f & 7) + 8 * ((f >> 3) ^ (row & 7))] = f2b(v);
            }
        }
        __syncthreads();   // (C) GEMM1 wst reads done + H complete
        {
            const short8v* gp = (const short8v*)(w2t + (size_t)e * 8192);
            #pragma unroll
            for (int i = 0; i < 4; ++i)
                *(short8v*)&wst[(i * 256 + tid) * 8] = gp[i * 256 + tid];
        }
        __syncthreads();   // (D) w2e ready
        f32x4 eo[4];
        #pragma unroll
        for (int i = 0; i < 4; ++i) eo[i] = (f32x4)0.f;
        #pragma unroll
        for (int st = 0; st < 4; ++st) {
            int chunkA = (st * 4 + g) ^ (row0 & 7);
            short8v a2 = *(const short8v*)&fAH[row0 * 128 + chunkA * 8];
            #pragma unroll
            for (int nt = 0; nt < 4; ++nt) {
                int n = nt * 16 + l15;
                int chunk = (st * 4 + g) ^ (n & 7);
                short8v b = *(const short8v*)&wst[n * 128 + chunk * 8];
                eo[nt] = __builtin_amdgcn_mfma_f32_16x16x32_bf16(a2, b, eo[nt], 0, 0, 0);
            }
        }
        #pragma unroll
        for (int nt = 0; nt < 4; ++nt) {
            int c = nt * 16 + l15;
            float bb = b2m[e * 64 + c];
            #pragma unroll
            for (int r = 0; r < 4; ++r) {
                float gt = gate[(rowb + r) * 4 + e];
                dacc[nt][r] += gt * (eo[nt][r] + bb);
            }
        }
    }
    __syncthreads();
    #pragma unroll
    for (int nt = 0; nt < 4; ++nt) {
        int c = nt * 16 + l15;
        #pragma unroll
        for (int r = 0; r < 4; ++r)
            fld[(rowb + r) * 65 + c] += dacc[nt][r];
    }
    __syncthreads();
    #pragma unroll
    for (int r = 0; r < 16; ++r) {
        int idx = r * 256 + tid;
        int c = idx >> 6, tok = idx & 63;
        float val = fld[tok * 65 + c];
        size_t xi_ = ((size_t)t * 32 + (c & 31)) * PX + px0 + tok;
        float xv = (c < 32) ? xre[xi_] : xim[xi_];
        out[(size_t)(c < 32 ? 0 : 4194304) + xi_] = val + xv;
    }
}

extern "C" void kernel_launch(void* const* d_in, const int* in_sizes, int n_in,
                              void* d_out, int out_size, void* d_ws, size_t ws_size,
                              hipStream_t stream) {
    const float* xre   = (const float*)d_in[0];
    const float* xim   = (const float*)d_in[1];
    const float* dt    = (const float*)d_in[2];
    const float* epsre = (const float*)d_in[3];
    const float* epsim = (const float*)d_in[4];
    const float* ln1g  = (const float*)d_in[5];
    const float* ln1b  = (const float*)d_in[6];
    const float* ln2g  = (const float*)d_in[7];
    const float* ln2b  = (const float*)d_in[8];
    const float* convw = (const float*)d_in[9];
    const float* convb = (const float*)d_in[10];
    const float* encre = (const float*)d_in[11];
    const float* encim = (const float*)d_in[12];
    const float* decre = (const float*)d_in[13];
    const float* decim = (const float*)d_in[14];
    const float* lamre = (const float*)d_in[15];
    const float* lamim = (const float*)d_in[16];
    const float* alpha = (const float*)d_in[17];
    const float* fwre  = (const float*)d_in[18];
    const float* fwim  = (const float*)d_in[19];
    const float* wg    = (const float*)d_in[20];
    const float* w1    = (const float*)d_in[21];
    const float* b1    = (const float*)d_in[22];
    const float* w2    = (const float*)d_in[23];
    const float* b2    = (const float*)d_in[24];
    float* out = (float*)d_out;

    float* ws = (float*)d_ws;
    unsigned short* xpad = (unsigned short*)ws;   // region A: xpad bf16 then xo f32
    float* xo   = ws;
    float* xs   = ws + 8388608;         // NHWC f32: conv out -> U (in-place) -> W
    float* mean = ws + 16777216;
    float* tabs = ws + 16779264;
    unsigned short* w1t = (unsigned short*)(ws + 16783360);
    unsigned short* w2t = w1t + 32768;
    unsigned short* w9t = w2t + 32768;
    unsigned short* benct = w9t + 36864;
    unsigned short* bdect = benct + 4096;

    k0_prep<<<432, 256, 0, stream>>>(w1, w2, convw, encre, encim, decre, decim,
                                     w1t, w2t, w9t, benct, bdect);
    kz_halo<<<33, 256, 0, stream>>>(xpad);
    k1_ln1<<<512, 256, 0, stream>>>(xre, xim, ln1g, ln1b, xpad);
    k2_conv<<<512, 256, 0, stream>>>(xpad, w9t, convb, xs);
    k3_mean<<<32, 256, 0, stream>>>(xs, mean);
    k4_ops<<<1, 256, 0, stream>>>(dt, lamre, lamim, alpha, fwre, fwim, mean,
                                  tabs, out + 8388608);
    k5_gemm<true><<<2048, 256, 0, stream>>>(xs, benct, tabs, xs);   // u*forcing
    k5b_scan<<<512, 256, 0, stream>>>(xs, tabs, dt, epsre, epsim);  // scan+noise
    k5_gemm<false><<<2048, 256, 0, stream>>>(xs, bdect, tabs, xo);  // dec
    k6_moe<<<2048, 256, 0, stream>>>(xo, ln2g, ln2b, wg, w1t, b1, w2t, b2,
                                     xre, xim, out);
}

// Round 9
// 259.910 us; speedup vs baseline: 4.1704x; 1.1137x over previous
//
#include <hip/hip_runtime.h>
#include <math.h>

#define PX 4096   // 64*64
#define TT 32
#define DD 32
#define CC 64     // 2*D
#define PW 66     // padded width
#define PPX 4356  // 66*66

typedef __attribute__((ext_vector_type(8))) short short8v;
typedef __attribute__((ext_vector_type(4))) float f32x4;

__device__ __forceinline__ float gelu_fast(float x) {
    // gelu_tanh(x) == x * sigmoid(2z), z = 0.7978845608*(x + 0.044715 x^3)
    float u = x * x;
    float a = x * (1.5957691216057308f + 0.07135481627f * u);
    return x / (1.0f + __expf(-a));
}

__device__ __forceinline__ unsigned short f2b(float x) {
    union { float f; unsigned u; } v; v.f = x;
    unsigned r = v.u + 0x7FFF + ((v.u >> 16) & 1);
    return (unsigned short)(r >> 16);
}

__device__ __forceinline__ float b2f(unsigned short b) {
    union { unsigned u; float f; } v; v.u = ((unsigned)b) << 16;
    return v.f;
}

// ---------------- K1: LN1 (64ch) fused -> padded bf16 NHWC ------------------
__global__ __launch_bounds__(256) void k1_ln1(
        const float* __restrict__ xre, const float* __restrict__ xim,
        const float* __restrict__ g, const float* __restrict__ b,
        unsigned short* __restrict__ xpad) {
    int gid = blockIdx.x * 256 + threadIdx.x;   // t*4096 + px
    int t = gid >> 12, px = gid & 4095;
    int row = px >> 6, col = px & 63;
    const float* pr = xre + (size_t)t * DD * PX + px;
    const float* pi = xim + (size_t)t * DD * PX + px;
    float s = 0.f, ss = 0.f;
    #pragma unroll
    for (int d = 0; d < DD; ++d) {
        float vr = pr[d * PX], vi = pi[d * PX];
        s += vr + vi; ss += vr * vr + vi * vi;
    }
    float m = s * (1.f / 64.f);
    float var = ss * (1.f / 64.f) - m * m;
    float rs = rsqrtf(var + 1e-5f);
    unsigned short* o = xpad + ((size_t)t * PPX + (row + 1) * PW + (col + 1)) * 64;
    #pragma unroll
    for (int j = 0; j < 8; ++j) {
        short8v v8;
        #pragma unroll
        for (int dd = 0; dd < 8; ++dd) {
            int ch = j * 8 + dd;
            float v = (ch < 32) ? (pr[ch * PX] - m) * rs * g[ch] + b[ch]
                                : (pi[(ch - 32) * PX] - m) * rs * g[ch] + b[ch];
            v8[dd] = (short)f2b(v);
        }
        *(short8v*)&o[j * 8] = v8;
    }
}

// ---------------- KZ: zero the halo of xpad ---------------------------------
__global__ __launch_bounds__(256) void kz_halo(unsigned short* __restrict__ xpad) {
    int gid = blockIdx.x * 256 + threadIdx.x;
    if (gid >= 32 * 260) return;
    int im = gid / 260, h = gid % 260;
    int row, col;
    if (h < 66)       { row = 0;  col = h; }
    else if (h < 132) { row = 65; col = h - 66; }
    else { int hh = h - 132; row = 1 + (hh >> 1); col = (hh & 1) * 65; }
    unsigned short* p = xpad + ((size_t)im * PPX + row * PW + col) * 64;
    short8v z = (short8v)0;
    #pragma unroll
    for (int j = 0; j < 8; ++j) *(short8v*)&p[j * 8] = z;
}

// ---------------- K0: prep — bf16/transpose/swizzle all weight matrices -----
__global__ __launch_bounds__(256) void k0_prep(
        const float* __restrict__ w1, const float* __restrict__ w2,
        const float* __restrict__ convw,
        const float* __restrict__ encre, const float* __restrict__ encim,
        const float* __restrict__ decre, const float* __restrict__ decim,
        unsigned short* __restrict__ w1t, unsigned short* __restrict__ w2t,
        unsigned short* __restrict__ w9t,
        unsigned short* __restrict__ benct, unsigned short* __restrict__ bdect) {
    int gid = blockIdx.x * 256 + threadIdx.x;
    if (gid < 32768) {
        int idx = gid;
        int e = idx >> 13, r = idx & 8191;
        int f = r >> 6, p = r & 63;
        int c = (p & 7) + 8 * ((p >> 3) ^ (f & 7));
        w1t[idx] = f2b(w1[((size_t)e * 64 + c) * 128 + f]);
    } else if (gid < 65536) {
        int idx = gid - 32768;
        int e = idx >> 13, r = idx & 8191;
        int n = r >> 7, p = r & 127;
        int f = (p & 7) + 8 * ((p >> 3) ^ (n & 7));
        w2t[idx] = f2b(w2[((size_t)e * 128 + f) * 64 + n]);
    } else if (gid < 102400) {
        int idx = gid - 65536;
        int tap = idx >> 12, rem = idx & 4095;
        int n = rem >> 6, p = rem & 63;
        int k = (p & 7) + 8 * ((p >> 3) ^ (n & 7));
        w9t[idx] = f2b(convw[((size_t)n * 64 + k) * 9 + tap]);
    } else if (gid < 110592) {
        int idx = gid - 102400;
        const float* Rr = (idx < 4096) ? encre : decre;
        const float* Ri = (idx < 4096) ? encim : decim;
        unsigned short* dst = (idx < 4096) ? benct : bdect;
        idx &= 4095;
        int n = idx >> 6, p = idx & 63;
        int k = (p & 7) + 8 * ((p >> 3) ^ (n & 7));
        float v;
        if (n < 32) v = (k < 32) ? Rr[k * 32 + n] : -Ri[(k - 32) * 32 + n];
        else        v = (k < 32) ? Ri[k * 32 + (n - 32)] : Rr[(k - 32) * 32 + (n - 32)];
        dst[idx] = f2b(v);
    }
}

// ---------------- K2: 3x3 conv 64->64 as 9-tap implicit GEMM (bf16 MFMA) ----
__global__ __launch_bounds__(256, 2) void k2_conv(
        const unsigned short* __restrict__ xpad,
        const unsigned short* __restrict__ w9t,
        const float* __restrict__ bias, float* __restrict__ xs) {
    __shared__ __align__(16) unsigned short wst[36864];   // 9 taps x 64oc x 64ic swz
    int tid = threadIdx.x;
    int bid = blockIdx.x;
    int lb = (bid & 7) * 64 + (bid >> 3);   // bijective (512 % 8 == 0)
    int t = lb >> 4, rg = lb & 15;
    int lane = tid & 63, wv = tid >> 6;
    int l15 = lane & 15, g = lane >> 4;
    #pragma unroll
    for (int i = 0; i < 18; ++i) {
        int idx = i * 256 + tid;
        *(short8v*)&wst[idx * 8] = *(const short8v*)&w9t[idx * 8];
    }
    __syncthreads();
    int r = rg * 4 + wv;
    const unsigned short* xb = xpad + (size_t)t * PPX * 64;
    f32x4 acc[4][4];
    #pragma unroll
    for (int m = 0; m < 4; ++m)
        #pragma unroll
        for (int nt = 0; nt < 4; ++nt) acc[m][nt] = (f32x4)0.f;

    #pragma unroll
    for (int kh = 0; kh < 3; ++kh) {
        #pragma unroll
        for (int kw = 0; kw < 3; ++kw) {
            int tap = kh * 3 + kw;
            #pragma unroll
            for (int kc = 0; kc < 2; ++kc) {
                short8v a[4];
                #pragma unroll
                for (int m = 0; m < 4; ++m) {
                    int pcol = m * 16 + l15 + kw;
                    a[m] = *(const short8v*)&xb[((size_t)(r + kh) * PW + pcol) * 64 + kc * 32 + g * 8];
                }
                #pragma unroll
                for (int nt = 0; nt < 4; ++nt) {
                    int n = nt * 16 + l15;
                    short8v bf = *(const short8v*)&wst[tap * 4096 + n * 64 + ((kc * 4 + g) ^ (n & 7)) * 8];
                    #pragma unroll
                    for (int m = 0; m < 4; ++m)
                        acc[m][nt] = __builtin_amdgcn_mfma_f32_16x16x32_bf16(a[m], bf, acc[m][nt], 0, 0, 0);
                }
            }
        }
    }
    float* dst = xs + ((size_t)t * PX + r * 64) * 64;
    #pragma unroll
    for (int nt = 0; nt < 4; ++nt) {
        float bo = bias[nt * 16 + l15];
        #pragma unroll
        for (int m = 0; m < 4; ++m) {
            #pragma unroll
            for (int reg = 0; reg < 4; ++reg) {
                int tok = m * 16 + g * 4 + reg;
                dst[(size_t)tok * 64 + nt * 16 + l15] = acc[m][nt][reg] + bo;
            }
        }
    }
}

// ---------------- K3: per-(t,c) spatial mean (NHWC input) -------------------
__global__ __launch_bounds__(256) void k3_mean(
        const float* __restrict__ xs, float* __restrict__ mean) {
    __shared__ f32x4 red[256];
    int t = blockIdx.x;
    int c4 = threadIdx.x & 15, q = threadIdx.x >> 4;
    const float* base = xs + (size_t)t * PX * 64 + c4 * 4;
    f32x4 s = (f32x4)0.f;
    for (int px = q; px < PX; px += 16)
        s += *(const f32x4*)&base[(size_t)px * 64];
    red[threadIdx.x] = s;
    __syncthreads();
    for (int st = 8; st > 0; st >>= 1) {
        if (q < st) red[q * 16 + c4] += red[(q + st) * 16 + c4];
        __syncthreads();
    }
    if (q == 0) {
        f32x4 v = red[c4] * (1.f / 4096.f);
        *(f32x4*)&mean[t * 64 + c4 * 4] = v;
    }
}

// ---------------- K4: decay/forcing tables + flux scan ----------------------
__global__ __launch_bounds__(256) void k4_ops(
        const float* __restrict__ dt, const float* __restrict__ lam_re,
        const float* __restrict__ lam_im, const float* __restrict__ alpha,
        const float* __restrict__ wre, const float* __restrict__ wim,
        const float* __restrict__ mean, float* __restrict__ tabs,
        float* __restrict__ outflux) {
    int tid = threadIdx.x;
    for (int idx = tid; idx < 1024; idx += 256) {
        int t = idx >> 5, d = idx & 31;
        float x = lam_re[d];
        float sp = (x > 0.f) ? x + log1pf(expf(-x)) : log1pf(expf(x));
        float lr = -sp, li = lam_im[d];
        float dtv = dt[t];
        float er = expf(lr * dtv);
        float dr = er * cosf(li * dtv);
        float di = er * sinf(li * dtv);
        float den = lr * lr + li * li;
        float fr = ((dr - 1.f) * lr + di * li) / den;
        float fi = (di * lr - (dr - 1.f) * li) / den;
        tabs[idx] = dr; tabs[1024 + idx] = di;
        tabs[2048 + idx] = fr; tabs[3072 + idx] = fi;
    }
    if (tid < 32) {
        int d = tid;
        float a = 1.f / (1.f + expf(-alpha[d]));
        float yr = 0.f, yi = 0.f;
        for (int t = 0; t < 32; ++t) {
            float xr = 0.f, xi = 0.f;
            for (int k = 0; k < 32; ++k) {
                float mr = mean[t * 64 + k], mi = mean[t * 64 + 32 + k];
                float wr = wre[k * 32 + d], wi = wim[k * 32 + d];
                xr += mr * wr - mi * wi;
                xi += mr * wi + mi * wr;
            }
            yr = a * yr + xr; yi = a * yi + xi;
        }
        outflux[d] = yr; outflux[32 + d] = yi;
    }
}

// ---------------- K5a/K5c: token GEMM (64 tok/block) vs 64x64 bf16 B --------
template<bool FORCING>
__global__ __launch_bounds__(256) void k5_gemm(
        const float* A, const unsigned short* __restrict__ Bt,
        const float* __restrict__ tabs, float* O) {
    __shared__ __align__(16) unsigned short fA[64 * 64];
    __shared__ __align__(16) unsigned short bst[64 * 64];
    int tid = threadIdx.x;
    int lane = tid & 63, wv = tid >> 6;
    size_t tok0 = (size_t)blockIdx.x * 64;
    #pragma unroll
    for (int i = 0; i < 2; ++i)
        *(short8v*)&bst[(i * 256 + tid) * 8] = *(const short8v*)&Bt[(i * 256 + tid) * 8];
    #pragma unroll
    for (int r = 0; r < 16; ++r) {
        int idx = r * 256 + tid;
        int tok = idx >> 6, c = idx & 63;
        fA[tok * 64 + (c & 7) + 8 * ((c >> 3) ^ (tok & 7))] = f2b(A[(tok0 + tok) * 64 + c]);
    }
    __syncthreads();
    int l15 = lane & 15, g = lane >> 4;
    int row0 = wv * 16 + l15;
    int rowb = wv * 16 + g * 4;
    short8v a1[2];
    #pragma unroll
    for (int st = 0; st < 2; ++st)
        a1[st] = *(const short8v*)&fA[row0 * 64 + (((st * 4 + g) ^ (row0 & 7))) * 8];
    f32x4 eo[4];
    #pragma unroll
    for (int i = 0; i < 4; ++i) eo[i] = (f32x4)0.f;
    #pragma unroll
    for (int st = 0; st < 2; ++st) {
        #pragma unroll
        for (int nt = 0; nt < 4; ++nt) {
            int n = nt * 16 + l15;
            short8v b = *(const short8v*)&bst[n * 64 + (((st * 4 + g) ^ (n & 7))) * 8];
            eo[nt] = __builtin_amdgcn_mfma_f32_16x16x32_bf16(a1[st], b, eo[nt], 0, 0, 0);
        }
    }
    if (FORCING) {
        int t = (int)(tok0 >> 12);
        #pragma unroll
        for (int p = 0; p < 2; ++p) {
            int d = p * 16 + l15;
            float fr = tabs[2048 + t * 32 + d], fi = tabs[3072 + t * 32 + d];
            #pragma unroll
            for (int r = 0; r < 4; ++r) {
                float ur = eo[p][r], ui = eo[p + 2][r];
                eo[p][r]     = ur * fr - ui * fi;
                eo[p + 2][r] = ur * fi + ui * fr;
            }
        }
    }
    #pragma unroll
    for (int nt = 0; nt < 4; ++nt) {
        int n = nt * 16 + l15;
        #pragma unroll
        for (int r = 0; r < 4; ++r)
            O[(tok0 + rowb + r) * 64 + n] = eo[nt][r];
    }
}

// ---------------- K5b: time scan + noise, pure streaming (in-place) ---------
__global__ __launch_bounds__(256) void k5b_scan(
        float* U, const float* __restrict__ tabs, const float* __restrict__ dt,
        const float* __restrict__ eps_re, const float* __restrict__ eps_im) {
    int gid = blockIdx.x * 256 + threadIdx.x;   // px*32 + d
    int px = gid >> 5, d = gid & 31;
    float Yr = 0.f, Yi = 0.f;
    for (int t = 0; t < TT; ++t) {
        size_t tok = (size_t)t * PX + px;
        float usr = U[tok * 64 + d], usi = U[tok * 64 + 32 + d];
        float dr = tabs[t * 32 + d], di = tabs[1024 + t * 32 + d];
        float nYr = dr * Yr - di * Yi + usr;
        float nYi = dr * Yi + di * Yr + usi;
        Yr = nYr; Yi = nYi;
        float s = 0.01f * sqrtf(dt[t]);
        size_t ei = tok * 32 + d;
        float epr = eps_re[ei], epi = eps_im[ei];
        U[tok * 64 + d]      = Yr + s * (Yr * epr - Yi * epi);
        U[tok * 64 + 32 + d] = Yi + s * (Yr * epi + Yi * epr);
    }
}

// ---------------- K6: LN2 + gated MoE MLP — transposed MFMA, reg-resident ---
// Thread = (token = wv*16+l15, c-slice by g). f lives in B-fragments (regs);
// GEMM1: D^T = mfma(w1^T, f) -> 4 consecutive f-dims/thread -> b64 H writes.
// GEMM2: D^T = mfma(w2^T, H) -> 4 consecutive out-ch of OWN token -> reg gate.
// LDS: hdl (H bf16 / delta f32 union) + wst + wgl = 33.6 KB -> 4 blk/CU.
__global__ __launch_bounds__(256, 4) void k6_moe(
        const float* __restrict__ xo,
        const float* __restrict__ g2, const float* __restrict__ b2ln,
        const float* __restrict__ wg,
        const unsigned short* __restrict__ w1t, const float* __restrict__ b1,
        const unsigned short* __restrict__ w2t, const float* __restrict__ b2m,
        const float* __restrict__ xre, const float* __restrict__ xim,
        float* __restrict__ out) {
    __shared__ __align__(16) float hdl[64 * 65];           // H bf16[64][128] / delta f32[64][65]
    __shared__ __align__(16) unsigned short wst[8192];     // one weight matrix
    __shared__ float wgl[256];
    unsigned short* H = (unsigned short*)hdl;

    int tid = threadIdx.x;
    int lane = tid & 63;
    int wv = tid >> 6;
    int l15 = lane & 15, g = lane >> 4;
    int t = blockIdx.x >> 6;
    int px0 = (blockIdx.x & 63) * 64;
    int tok = wv * 16 + l15;          // this thread's token (B col / D col)
    int tsw = tok & 7;

    wgl[tid] = wg[tid];

    // load my 16 channels: c = st*32 + g*8 + j
    float f[16];
    {
        const float* src = xo + ((size_t)t * PX + px0 + tok) * 64 + g * 8;
        #pragma unroll
        for (int st = 0; st < 2; ++st) {
            float4 v0 = *(const float4*)&src[st * 32];
            float4 v1 = *(const float4*)&src[st * 32 + 4];
            f[st*8+0]=v0.x; f[st*8+1]=v0.y; f[st*8+2]=v0.z; f[st*8+3]=v0.w;
            f[st*8+4]=v1.x; f[st*8+5]=v1.y; f[st*8+6]=v1.z; f[st*8+7]=v1.w;
        }
    }
    // LN2 stats over the 4 lanes sharing this token (xor 16, 32)
    float s = 0.f, ss = 0.f;
    #pragma unroll
    for (int i = 0; i < 16; ++i) { s += f[i]; ss += f[i] * f[i]; }
    s += __shfl_xor(s, 16); ss += __shfl_xor(ss, 16);
    s += __shfl_xor(s, 32); ss += __shfl_xor(ss, 32);
    float m = s * (1.f / 64.f);
    float rs = rsqrtf(ss * (1.f / 64.f) - m * m + 1e-5f);
    #pragma unroll
    for (int st = 0; st < 2; ++st) {
        int c0 = st * 32 + g * 8;
        float4 gv0 = *(const float4*)&g2[c0],   gv1 = *(const float4*)&g2[c0 + 4];
        float4 bv0 = *(const float4*)&b2ln[c0], bv1 = *(const float4*)&b2ln[c0 + 4];
        f[st*8+0] = (f[st*8+0]-m)*rs*gv0.x + bv0.x;
        f[st*8+1] = (f[st*8+1]-m)*rs*gv0.y + bv0.y;
        f[st*8+2] = (f[st*8+2]-m)*rs*gv0.z + bv0.z;
        f[st*8+3] = (f[st*8+3]-m)*rs*gv0.w + bv0.w;
        f[st*8+4] = (f[st*8+4]-m)*rs*gv1.x + bv1.x;
        f[st*8+5] = (f[st*8+5]-m)*rs*gv1.y + bv1.y;
        f[st*8+6] = (f[st*8+6]-m)*rs*gv1.z + bv1.z;
        f[st*8+7] = (f[st*8+7]-m)*rs*gv1.w + bv1.w;
    }
    __syncthreads();   // wgl visible
    // gate logits (partial over my 16 c) -> xor-reduce -> softmax in regs
    float gt[4];
    {
        float g0 = 0.f, g1 = 0.f, g2_ = 0.f, g3 = 0.f;
        #pragma unroll
        for (int st = 0; st < 2; ++st)
            #pragma unroll
            for (int j = 0; j < 8; ++j) {
                int c = st * 32 + g * 8 + j;
                float fv = f[st * 8 + j];
                g0 += fv * wgl[c*4];   g1 += fv * wgl[c*4+1];
                g2_ += fv * wgl[c*4+2]; g3 += fv * wgl[c*4+3];
            }
        g0 += __shfl_xor(g0, 16); g1 += __shfl_xor(g1, 16);
        g2_ += __shfl_xor(g2_, 16); g3 += __shfl_xor(g3, 16);
        g0 += __shfl_xor(g0, 32); g1 += __shfl_xor(g1, 32);
        g2_ += __shfl_xor(g2_, 32); g3 += __shfl_xor(g3, 32);
        float mx = fmaxf(fmaxf(g0, g1), fmaxf(g2_, g3));
        float e0 = expf(g0-mx), e1 = expf(g1-mx), e2 = expf(g2_-mx), e3 = expf(g3-mx);
        float inv = 1.f / (e0 + e1 + e2 + e3);
        gt[0] = e0*inv; gt[1] = e1*inv; gt[2] = e2*inv; gt[3] = e3*inv;
    }
    // pack f -> B fragments (k = c within 32-chunk: lane supplies k = g*8+j)
    short8v bf1[2];
    #pragma unroll
    for (int st = 0; st < 2; ++st)
        #pragma unroll
        for (int j = 0; j < 8; ++j)
            bf1[st][j] = (short)f2b(f[st * 8 + j]);

    f32x4 dacc[4];
    #pragma unroll
    for (int i = 0; i < 4; ++i) dacc[i] = (f32x4)0.f;

    for (int e = 0; e < 4; ++e) {
        __syncthreads();   // (A) prev GEMM2 done reading wst/H
        {   // stage w1e (16 KB): w1t[f][c swz]
            const short8v* gp = (const short8v*)(w1t + (size_t)e * 8192);
            #pragma unroll
            for (int i = 0; i < 4; ++i)
                *(short8v*)&wst[(i * 256 + tid) * 8] = gp[i * 256 + tid];
        }
        __syncthreads();   // (B) w1e ready
        // GEMM1^T: H^T[f][tok] = mfma(A=w1^T rows f, B=f cols tok)
        f32x4 h[8];
        #pragma unroll
        for (int i = 0; i < 8; ++i) h[i] = (f32x4)0.f;
        #pragma unroll
        for (int st = 0; st < 2; ++st) {
            #pragma unroll
            for (int ft = 0; ft < 8; ++ft) {
                int fi = ft * 16 + l15;
                short8v a = *(const short8v*)&wst[fi * 64 + (((st * 4 + g) ^ (fi & 7))) * 8];
                h[ft] = __builtin_amdgcn_mfma_f32_16x16x32_bf16(a, bf1[st], h[ft], 0, 0, 0);
            }
        }
        // epilogue: 4 consecutive f-dims of MY token -> gelu -> one b64 write
        #pragma unroll
        for (int ft = 0; ft < 8; ++ft) {
            int f0 = ft * 16 + g * 4;
            float4 bb = *(const float4*)&b1[e * 128 + f0];
            unsigned short p0 = f2b(gelu_fast(h[ft][0] + bb.x));
            unsigned short p1 = f2b(gelu_fast(h[ft][1] + bb.y));
            unsigned short p2 = f2b(gelu_fast(h[ft][2] + bb.z));
            unsigned short p3 = f2b(gelu_fast(h[ft][3] + bb.w));
            unsigned long long pk = (unsigned long long)p0 | ((unsigned long long)p1 << 16)
                                  | ((unsigned long long)p2 << 32) | ((unsigned long long)p3 << 48);
            *(unsigned long long*)&H[tok * 128 + (f0 & 7) + 8 * ((f0 >> 3) ^ tsw)] = pk;
        }
        __syncthreads();   // (C) GEMM1 wst reads done + H complete
        {   // stage w2e (16 KB): w2t[n][f swz]
            const short8v* gp = (const short8v*)(w2t + (size_t)e * 8192);
            #pragma unroll
            for (int i = 0; i < 4; ++i)
                *(short8v*)&wst[(i * 256 + tid) * 8] = gp[i * 256 + tid];
        }
        __syncthreads();   // (D) w2e ready
        // GEMM2^T: eo^T[n][tok] = mfma(A=w2^T rows n, B=H cols tok)
        f32x4 eo[4];
        #pragma unroll
        for (int i = 0; i < 4; ++i) eo[i] = (f32x4)0.f;
        #pragma unroll
        for (int st = 0; st < 4; ++st) {
            short8v bh = *(const short8v*)&H[tok * 128 + (((st * 4 + g) ^ tsw)) * 8];
            #pragma unroll
            for (int nt = 0; nt < 4; ++nt) {
                int n = nt * 16 + l15;
                short8v a = *(const short8v*)&wst[n * 128 + (((st * 4 + g) ^ (n & 7))) * 8];
                eo[nt] = __builtin_amdgcn_mfma_f32_16x16x32_bf16(a, bh, eo[nt], 0, 0, 0);
            }
        }
        float ge = gt[e];
        #pragma unroll
        for (int nt = 0; nt < 4; ++nt) {
            int n0 = nt * 16 + g * 4;
            float4 bb = *(const float4*)&b2m[e * 64 + n0];
            dacc[nt][0] += ge * (eo[nt][0] + bb.x);
            dacc[nt][1] += ge * (eo[nt][1] + bb.y);
            dacc[nt][2] += ge * (eo[nt][2] + bb.z);
            dacc[nt][3] += ge * (eo[nt][3] + bb.w);
        }
    }
    __syncthreads();   // all H reads done; reuse hdl as f32 delta [64][65]
    float* dl = hdl;
    #pragma unroll
    for (int nt = 0; nt < 4; ++nt) {
        int n0 = nt * 16 + g * 4;
        #pragma unroll
        for (int r = 0; r < 4; ++r)
            dl[tok * 65 + n0 + r] = dacc[nt][r];
    }
    __syncthreads();
    // final: out = x + (f + delta); f recovered from bf16 fragments
    #pragma unroll
    for (int st = 0; st < 2; ++st) {
        const float* xsrc = (st == 0) ? xre : xim;
        float* osrc = out + (st == 0 ? 0 : (size_t)4194304);
        #pragma unroll
        for (int j = 0; j < 8; ++j) {
            int c = st * 32 + g * 8 + j;
            float val = b2f((unsigned short)bf1[st][j]) + dl[tok * 65 + c];
            size_t xi_ = ((size_t)t * 32 + (c & 31)) * PX + px0 + tok;
            osrc[xi_] = val + xsrc[xi_];
        }
    }
}

extern "C" void kernel_launch(void* const* d_in, const int* in_sizes, int n_in,
                              void* d_out, int out_size, void* d_ws, size_t ws_size,
                              hipStream_t stream) {
    const float* xre   = (const float*)d_in[0];
    const float* xim   = (const float*)d_in[1];
    const float* dt    = (const float*)d_in[2];
    const float* epsre = (const float*)d_in[3];
    const float* epsim = (const float*)d_in[4];
    const float* ln1g  = (const float*)d_in[5];
    const float* ln1b  = (const float*)d_in[6];
    const float* ln2g  = (const float*)d_in[7];
    const float* ln2b  = (const float*)d_in[8];
    const float* convw = (const float*)d_in[9];
    const float* convb = (const float*)d_in[10];
    const float* encre = (const float*)d_in[11];
    const float* encim = (const float*)d_in[12];
    const float* decre = (const float*)d_in[13];
    const float* decim = (const float*)d_in[14];
    const float* lamre = (const float*)d_in[15];
    const float* lamim = (const float*)d_in[16];
    const float* alpha = (const float*)d_in[17];
    const float* fwre  = (const float*)d_in[18];
    const float* fwim  = (const float*)d_in[19];
    const float* wg    = (const float*)d_in[20];
    const float* w1    = (const float*)d_in[21];
    const float* b1    = (const float*)d_in[22];
    const float* w2    = (const float*)d_in[23];
    const float* b2    = (const float*)d_in[24];
    float* out = (float*)d_out;

    float* ws = (float*)d_ws;
    unsigned short* xpad = (unsigned short*)ws;   // region A: xpad bf16 then xo f32
    float* xo   = ws;
    float* xs   = ws + 8388608;         // NHWC f32: conv out -> U (in-place) -> W
    float* mean = ws + 16777216;
    float* tabs = ws + 16779264;
    unsigned short* w1t = (unsigned short*)(ws + 16783360);
    unsigned short* w2t = w1t + 32768;
    unsigned short* w9t = w2t + 32768;
    unsigned short* benct = w9t + 36864;
    unsigned short* bdect = benct + 4096;

    k0_prep<<<432, 256, 0, stream>>>(w1, w2, convw, encre, encim, decre, decim,
                                     w1t, w2t, w9t, benct, bdect);
    kz_halo<<<33, 256, 0, stream>>>(xpad);
    k1_ln1<<<512, 256, 0, stream>>>(xre, xim, ln1g, ln1b, xpad);
    k2_conv<<<512, 256, 0, stream>>>(xpad, w9t, convb, xs);
    k3_mean<<<32, 256, 0, stream>>>(xs, mean);
    k4_ops<<<1, 256, 0, stream>>>(dt, lamre, lamim, alpha, fwre, fwim, mean,
                                  tabs, out + 8388608);
    k5_gemm<true><<<2048, 256, 0, stream>>>(xs, benct, tabs, xs);   // u*forcing
    k5b_scan<<<512, 256, 0, stream>>>(xs, tabs, dt, epsre, epsim);  // scan+noise
    k5_gemm<false><<<2048, 256, 0, stream>>>(xs, bdect, tabs, xo);  // dec
    k6_moe<<<2048, 256, 0, stream>>>(xo, ln2g, ln2b, wg, w1t, b1, w2t, b2,
                                     xre, xim, out);
}